// Round 8
// baseline (476.068 us; speedup 1.0000x reference)
//
#include <hip/hip_runtime.h>

// NestedAttention MI355X round 8: key-split TLP. Block = 4 waves =
// 2 q-tiles x 2 key-halves (ks). Each wave: 36 x 32-key steps (round-6
// single-chain compute). ks-partials combined in-block via LDS:
// O = (O0+O1)/(l0+l1) (exact for no-max softmax). 5184 waves (2x round 6).
//
// ws layout (ushort elems):
//   Qf  [3i][4b][72 t][4 f][512]   @ OQ    (frag chunks, == Kf layout)
//   Kf  [3i][4b][72 t][4 f][512]   @ OK_
//   Vf  [3i][4b][72 t][2c][2rb][512] @ OV
//   combj [3j][4b][N][192g]        @ OC (+j*CSTR)
//   xf  [4b][72 nb][16 ks][512]    @ OXF   (x as B-frag chunks, bf16)
//   Wf  [9 s][16 ks][2 rb][512]    @ OWF   (weights as A-frag chunks)
// Frag chunk: chunk[lane*8+e] = Op[idx=lane&31][k=8*(lane>>5)+e]

#define BB 4
#define CC 256
#define NN_ 2304
#define RR 64

#define OQ 0
#define OK_ 1769472
#define OV 3538944
#define OC 5308416
#define CSTR 1769472
#define FR_IB 147456   // per (i,b) frag-buffer stride (= N*64)
#define OXF 10616832
#define OWF 12976128

typedef __bf16 bf16x8 __attribute__((ext_vector_type(8)));
typedef float f32x16 __attribute__((ext_vector_type(16)));
typedef unsigned short ushort8 __attribute__((ext_vector_type(8)));
typedef unsigned int uintx2 __attribute__((ext_vector_type(2)));
typedef unsigned int uintx4 __attribute__((ext_vector_type(4)));

__device__ __forceinline__ unsigned short f2bf(float f) {
    unsigned int u = __builtin_bit_cast(unsigned int, f);
    u = (u + 0x7FFFu + ((u >> 16) & 1u)) >> 16;
    return (unsigned short)u;
}
__device__ __forceinline__ float bf2f(unsigned short s) {
    unsigned int u = ((unsigned int)s) << 16;
    return __builtin_bit_cast(float, u);
}
__device__ __forceinline__ unsigned int pk_bf16(float lo, float hi) {
    unsigned int r;
    asm("v_cvt_pk_bf16_f32 %0, %1, %2" : "=v"(r) : "v"(lo), "v"(hi));
    return r;
}

// ---------------------------------------------------------------------------
// Prep (merged): bid<9 -> weights to A-frag chunks; else x to B-frag chunks.
// ---------------------------------------------------------------------------
__global__ __launch_bounds__(256) void prep_kernel(
    const float* __restrict__ x, const float* __restrict__ wq,
    const float* __restrict__ wk, const float* __restrict__ wv,
    unsigned short* __restrict__ wsb)
{
    int bid = blockIdx.x;
    int t = threadIdx.x;
    if (bid < 9) {
        int s = bid;
        int type = s / 3, i = s % 3;
        const float* wsel = (type == 0) ? wq : (type == 1 ? wk : wv);
        const float scale = (type == 0) ? 0.18033688011112042f : 1.0f;  // 0.125*log2e
        unsigned short* dst = wsb + OWF + s * 16384;
        #pragma unroll
        for (int p = 0; p < 8; ++p) {
            int u = t + 256 * p;
            int ks = u >> 7, rb = (u >> 6) & 1, lo = u & 63;
            int row = rb * 32 + (lo & 31), c = ks * 16 + 8 * (lo >> 5);
            const float* src = wsel + ((i * 64 + row) * 256 + c);
            float4 f0 = *(const float4*)(src);
            float4 f1 = *(const float4*)(src + 4);
            uintx4 pwv = {pk_bf16(f0.x * scale, f0.y * scale),
                          pk_bf16(f0.z * scale, f0.w * scale),
                          pk_bf16(f1.x * scale, f1.y * scale),
                          pk_bf16(f1.z * scale, f1.w * scale)};
            *(uintx4*)(dst + (ks * 2 + rb) * 512 + lo * 8) = pwv;
        }
        return;
    }
    __shared__ __align__(16) float xs[64 * 132];
    int xb = bid - 9;
    int cq  = xb & 3;
    int nt2 = (xb >> 2) % 18;
    int b   = xb / 72;
    int c0 = cq * 64, n0 = nt2 * 128;
    #pragma unroll
    for (int p = 0; p < 8; ++p) {
        int u = t + 256 * p;
        int cl = u >> 5, nq = (u & 31) * 4;
        *(float4*)&xs[cl * 132 + nq] =
            *(const float4*)&x[((size_t)(b * CC + c0 + cl)) * NN_ + n0 + nq];
    }
    __syncthreads();
    unsigned short* xfb = wsb + OXF + ((size_t)b) * 72 * 16 * 512;
    #pragma unroll
    for (int p = 0; p < 4; ++p) {
        int u = t + 256 * p;
        int nb_l = u >> 8, ks_l = (u >> 6) & 3, lo = u & 63;
        int hh = lo >> 5, idx = lo & 31;
        int clb = ks_l * 16 + 8 * hh;
        int nn = nb_l * 32 + idx;
        unsigned int pw[4];
        #pragma unroll
        for (int d = 0; d < 4; ++d) {
            float a  = xs[(clb + 2 * d) * 132 + nn];
            float bb = xs[(clb + 2 * d + 1) * 132 + nn];
            pw[d] = pk_bf16(a, bb);
        }
        int nb = nt2 * 4 + nb_l, ks = cq * 4 + ks_l;
        *(uintx4*)(xfb + (nb * 16 + ks) * 512 + lo * 8) =
            (uintx4){pw[0], pw[1], pw[2], pw[3]};
    }
}

// ---------------------------------------------------------------------------
// Kernel: MFMA projection (unchanged structure).
// ---------------------------------------------------------------------------
__global__ __launch_bounds__(256) void proj_mfma(unsigned short* __restrict__ wsb)
{
    int bid = blockIdx.x;
    int s = bid / 72;
    int rem = bid % 72;
    int b = rem / 18, nb4 = rem % 18;
    int type = s / 3, i = s % 3;
    int t = threadIdx.x;
    int w = t >> 6, lane = t & 63;
    int lq = lane & 31, h = lane >> 5;
    int nb = nb4 * 4 + w;

    const unsigned short* wf = wsb + OWF + s * 16384 + lane * 8;
    const unsigned short* xf = wsb + OXF + ((size_t)(b * 72 + nb) * 16) * 512 + lane * 8;

    f32x16 o0 = {}, o1 = {};
    if (type < 2) {
        #pragma unroll
        for (int ks = 0; ks < 16; ++ks) {
            bf16x8 a0 = *(const bf16x8*)(wf + ks * 1024);
            bf16x8 a1 = *(const bf16x8*)(wf + ks * 1024 + 512);
            bf16x8 bx = *(const bf16x8*)(xf + ks * 512);
            o0 = __builtin_amdgcn_mfma_f32_32x32x16_bf16(a0, bx, o0, 0, 0, 0);
            o1 = __builtin_amdgcn_mfma_f32_32x32x16_bf16(a1, bx, o1, 0, 0, 0);
        }
    } else {
        #pragma unroll
        for (int ks = 0; ks < 16; ++ks) {
            bf16x8 a0 = *(const bf16x8*)(wf + ks * 1024);
            bf16x8 a1 = *(const bf16x8*)(wf + ks * 1024 + 512);
            bf16x8 bx = *(const bf16x8*)(xf + ks * 512);
            o0 = __builtin_amdgcn_mfma_f32_32x32x16_bf16(bx, a0, o0, 0, 0, 0);
            o1 = __builtin_amdgcn_mfma_f32_32x32x16_bf16(bx, a1, o1, 0, 0, 0);
        }
    }

    unsigned short* dstbase =
        wsb + ((type == 0) ? OQ : (type == 1 ? OK_ : OV)) +
        ((size_t)(i * 4 + b)) * FR_IB + nb * 2048;

    if (type < 2) {
        #pragma unroll
        for (int g = 0; g < 4; ++g) {
            int kd = 8 * g + 4 * h;
            int off = (kd >> 4) * 512 + ((kd >> 3) & 1) * 256 + lq * 8 + (kd & 7);
            *(uintx2*)(dstbase + off) =
                (uintx2){pk_bf16(o0[4 * g], o0[4 * g + 1]),
                         pk_bf16(o0[4 * g + 2], o0[4 * g + 3])};
            int kd2 = kd + 32;
            int off2 = (kd2 >> 4) * 512 + ((kd2 >> 3) & 1) * 256 + lq * 8 + (kd2 & 7);
            *(uintx2*)(dstbase + off2) =
                (uintx2){pk_bf16(o1[4 * g], o1[4 * g + 1]),
                         pk_bf16(o1[4 * g + 2], o1[4 * g + 3])};
        }
    } else {
        #pragma unroll
        for (int g = 0; g < 4; ++g) {
            int off = (g >> 1) * 1024 + (g & 1) * 256 + lq * 8 + 4 * h;
            *(uintx2*)(dstbase + off) =
                (uintx2){pk_bf16(o0[4 * g], o0[4 * g + 1]),
                         pk_bf16(o0[4 * g + 2], o0[4 * g + 3])};
            *(uintx2*)(dstbase + off + 512) =
                (uintx2){pk_bf16(o1[4 * g], o1[4 * g + 1]),
                         pk_bf16(o1[4 * g + 2], o1[4 * g + 3])};
        }
    }
}

// ---------------------------------------------------------------------------
// Kernel: MFMA flash attention, key-split. Block = 4 waves (256 thr):
// wave w -> ks = w&1 (key half), qloc = w>>1 (q-tile). Two LDS streams
// (one per ks), each double-buffered 2x8KB, shared by the 2 q-tile waves.
// Wave = 36 x 32-key steps over keys [ks*1152, ks*1152+1152).
// Epilogue: ks1 posts (O,l) to LDS; ks0 combines, normalizes, stores.
// ---------------------------------------------------------------------------
__global__ __launch_bounds__(256, 5) void attn_kernel(unsigned short* __restrict__ wsb)
{
    __shared__ __align__(16) unsigned char lds_raw[32768];
    unsigned short* kvbuf = (unsigned short*)lds_raw;  // [2 ks][2 buf][4096]
    float* fl = (float*)lds_raw;                       // epilogue reuse

    int bid = blockIdx.x;
    int wid = (bid & 7) * 162 + (bid >> 3);   // XCD-contiguous (1296 = 8*162)
    int s12 = wid / 108;                      // (j,b) reuse set
    int rem = wid % 108;
    int j = s12 >> 2, b = s12 & 3;
    int i = rem / 36;
    int qp = rem % 36;
    int w = threadIdx.x >> 6;
    int ks = w & 1, qloc = w >> 1;
    int lane = threadIdx.x & 63;
    int lq = lane & 31;
    int h = lane >> 5;
    int q0 = (qp * 2 + qloc) * 32;

    const unsigned short* qtf = wsb + OQ + ((size_t)(i * 4 + b)) * FR_IB +
                                (q0 >> 5) * 2048 + lane * 8;
    const unsigned short* kf = wsb + OK_ + ((size_t)(j * 4 + b)) * FR_IB;
    const unsigned short* vf = wsb + OV + ((size_t)(j * 4 + b)) * FR_IB;

    bf16x8 bq0 = *(const bf16x8*)(qtf + 0);
    bf16x8 bq1 = *(const bf16x8*)(qtf + 512);
    bf16x8 bq2 = *(const bf16x8*)(qtf + 1024);
    bf16x8 bq3 = *(const bf16x8*)(qtf + 1536);

    uintx4 onesw = {0x3F803F80u, 0x3F803F80u, 0x3F803F80u, 0x3F803F80u};
    bf16x8 ones = __builtin_bit_cast(bf16x8, onesw);

    // staging: within stream ks, wave qloc0 stages K chunks (slots 0-3),
    // qloc1 stages V chunks (slots 4-7). 36 tiles starting at ks*36.
    const unsigned short* sbase =
        ((qloc == 0) ? kf : vf) + (size_t)(ks * 36) * 2048 + lane * 8;
    int dbase = ks * 8192 + qloc * 2048 + lane * 8;
    int sread = ks * 8192;

    f32x16 o0 = {}, o1 = {}, lacc = {};

    auto compute_step = [&](const unsigned short* base) {
        bf16x8 k0 = *(const bf16x8*)(base + 0 * 512 + lane * 8);
        bf16x8 k1 = *(const bf16x8*)(base + 1 * 512 + lane * 8);
        bf16x8 k2 = *(const bf16x8*)(base + 2 * 512 + lane * 8);
        bf16x8 k3 = *(const bf16x8*)(base + 3 * 512 + lane * 8);
        bf16x8 v00 = *(const bf16x8*)(base + 4 * 512 + lane * 8);  // c0,rb0
        bf16x8 v10 = *(const bf16x8*)(base + 5 * 512 + lane * 8);  // c0,rb1
        bf16x8 v01 = *(const bf16x8*)(base + 6 * 512 + lane * 8);  // c1,rb0
        bf16x8 v11 = *(const bf16x8*)(base + 7 * 512 + lane * 8);  // c1,rb1

        f32x16 s = {};
        __builtin_amdgcn_s_setprio(1);
        s = __builtin_amdgcn_mfma_f32_32x32x16_bf16(k0, bq0, s, 0, 0, 0);
        s = __builtin_amdgcn_mfma_f32_32x32x16_bf16(k1, bq1, s, 0, 0, 0);
        s = __builtin_amdgcn_mfma_f32_32x32x16_bf16(k2, bq2, s, 0, 0, 0);
        s = __builtin_amdgcn_mfma_f32_32x32x16_bf16(k3, bq3, s, 0, 0, 0);
        __builtin_amdgcn_s_setprio(0);

        // raw exp2 — no max subtraction (|S|log2e bounded ~12 by input norms)
        #pragma unroll
        for (int r = 0; r < 16; ++r) s[r] = exp2f(s[r]);

        __builtin_amdgcn_s_setprio(1);
        {   // keys 0..15 of this 32-key step
            unsigned int a0 = pk_bf16(s[0], s[1]);
            unsigned int a1 = pk_bf16(s[2], s[3]);
            unsigned int b0 = pk_bf16(s[4], s[5]);
            unsigned int b1 = pk_bf16(s[6], s[7]);
            uintx2 r0 = __builtin_amdgcn_permlane32_swap(a0, b0, false, false);
            uintx2 r1 = __builtin_amdgcn_permlane32_swap(a1, b1, false, false);
            uintx4 pwv = {r0[0], r1[0], r0[1], r1[1]};
            bf16x8 pa = __builtin_bit_cast(bf16x8, pwv);
            o0 = __builtin_amdgcn_mfma_f32_32x32x16_bf16(v00, pa, o0, 0, 0, 0);
            o1 = __builtin_amdgcn_mfma_f32_32x32x16_bf16(v10, pa, o1, 0, 0, 0);
            lacc = __builtin_amdgcn_mfma_f32_32x32x16_bf16(ones, pa, lacc, 0, 0, 0);
        }
        {   // keys 16..31
            unsigned int a0 = pk_bf16(s[8], s[9]);
            unsigned int a1 = pk_bf16(s[10], s[11]);
            unsigned int b0 = pk_bf16(s[12], s[13]);
            unsigned int b1 = pk_bf16(s[14], s[15]);
            uintx2 r0 = __builtin_amdgcn_permlane32_swap(a0, b0, false, false);
            uintx2 r1 = __builtin_amdgcn_permlane32_swap(a1, b1, false, false);
            uintx4 pwv = {r0[0], r1[0], r0[1], r1[1]};
            bf16x8 pa = __builtin_bit_cast(bf16x8, pwv);
            o0 = __builtin_amdgcn_mfma_f32_32x32x16_bf16(v01, pa, o0, 0, 0, 0);
            o1 = __builtin_amdgcn_mfma_f32_32x32x16_bf16(v11, pa, o1, 0, 0, 0);
            lacc = __builtin_amdgcn_mfma_f32_32x32x16_bf16(ones, pa, lacc, 0, 0, 0);
        }
        __builtin_amdgcn_s_setprio(0);
    };

    // ---- prologue: stage step 0, prefetch step 1 ----
    ushort8 pre0 = *(const ushort8*)(sbase + 0 * 512);
    ushort8 pre1 = *(const ushort8*)(sbase + 1 * 512);
    ushort8 pre2 = *(const ushort8*)(sbase + 2 * 512);
    ushort8 pre3 = *(const ushort8*)(sbase + 3 * 512);
    *(ushort8*)(kvbuf + dbase + 0 * 512) = pre0;
    *(ushort8*)(kvbuf + dbase + 1 * 512) = pre1;
    *(ushort8*)(kvbuf + dbase + 2 * 512) = pre2;
    *(ushort8*)(kvbuf + dbase + 3 * 512) = pre3;
    pre0 = *(const ushort8*)(sbase + 2048 + 0 * 512);
    pre1 = *(const ushort8*)(sbase + 2048 + 1 * 512);
    pre2 = *(const ushort8*)(sbase + 2048 + 2 * 512);
    pre3 = *(const ushort8*)(sbase + 2048 + 3 * 512);
    __syncthreads();

    int cur = 0;
    for (int step = 0; step < 36; ++step) {
        if (step + 1 < 36) {   // write prefetched step+1 into other buffer
            unsigned short* wb = kvbuf + dbase + (cur ^ 1) * 4096;
            *(ushort8*)(wb + 0 * 512) = pre0;
            *(ushort8*)(wb + 1 * 512) = pre1;
            *(ushort8*)(wb + 2 * 512) = pre2;
            *(ushort8*)(wb + 3 * 512) = pre3;
        }
        if (step + 2 < 36) {   // issue loads for step+2
            const unsigned short* sp = sbase + (step + 2) * 2048;
            pre0 = *(const ushort8*)(sp + 0 * 512);
            pre1 = *(const ushort8*)(sp + 1 * 512);
            pre2 = *(const ushort8*)(sp + 2 * 512);
            pre3 = *(const ushort8*)(sp + 3 * 512);
        }
        compute_step(kvbuf + sread + cur * 4096);
        __syncthreads();
        cur ^= 1;
    }

    // ---- combine ks halves: O = (O0+O1)/(l0+l1) ----
    // (last loop iteration ended with __syncthreads; kvbuf reusable)
    int off = qloc * 2112;
    if (ks == 1) {
        #pragma unroll
        for (int reg = 0; reg < 16; ++reg) {
            fl[off + reg * 64 + lane] = o0[reg];
            fl[off + 1024 + reg * 64 + lane] = o1[reg];
        }
        fl[off + 2048 + lane] = lacc[0];
    }
    __syncthreads();
    if (ks == 1) return;

    #pragma unroll
    for (int reg = 0; reg < 16; ++reg) {
        o0[reg] += fl[off + reg * 64 + lane];
        o1[reg] += fl[off + 1024 + reg * 64 + lane];
    }
    float l_tot = lacc[0] + fl[off + 2048 + lane];
    __syncthreads();   // fl region now reusable for transpose

    float inv = 1.f / l_tot;
    o0 *= inv; o1 *= inv;

    // transpose O^T (rows r_v, col=own q) -> comb rows [n][g] via LDS
    float* tw = fl + qloc * 2080;
    #pragma unroll
    for (int reg = 0; reg < 16; ++reg) {
        int rv = (reg & 3) + 8 * (reg >> 2) + 4 * h;
        tw[lq * 65 + rv] = o0[reg];
        tw[lq * 65 + 32 + rv] = o1[reg];
    }
    int q = lane >> 1, half = lane & 1;
    unsigned int pw[16];
    #pragma unroll
    for (int d = 0; d < 16; ++d) {
        float a = tw[q * 65 + half * 32 + 2 * d];
        float bv = tw[q * 65 + half * 32 + 2 * d + 1];
        pw[d] = (unsigned int)f2bf(a) | ((unsigned int)f2bf(bv) << 16);
    }
    unsigned int* dstp = (unsigned int*)(wsb + OC + (size_t)j * CSTR +
                        ((size_t)(b * NN_ + q0 + q)) * 192 + i * 64 + half * 32);
    #pragma unroll
    for (int t4 = 0; t4 < 4; ++t4)
        *(uintx4*)(dstp + t4 * 4) = (uintx4){pw[4 * t4], pw[4 * t4 + 1], pw[4 * t4 + 2], pw[4 * t4 + 3]};
}

// ---------------------------------------------------------------------------
// Kernel: out[b,c,n] = sum_g wo[c,g] * (sum_j combj[b,n,g]); y = x*sigmoid.
// ---------------------------------------------------------------------------
__global__ __launch_bounds__(256) void out_kernel(
    const float* __restrict__ x, const float* __restrict__ wo,
    const unsigned short* __restrict__ wsb, float* __restrict__ out)
{
    __shared__ __align__(16) float cs[64][196];
    int bid  = blockIdx.x;
    int cq   = bid & 3;
    int tile = (bid >> 2) % 36;
    int b    = bid / 144;
    int n0   = tile * 64;
    int t    = threadIdx.x;

    const unsigned short* cmb = wsb + OC;
    for (int u = t * 8; u < 64 * 192; u += 256 * 8) {
        int n = u / 192, g = u % 192;
        size_t base = ((size_t)(b * NN_ + n0 + n)) * 192 + g;
        ushort8 c0 = *(const ushort8*)(cmb + base);
        ushort8 c1 = *(const ushort8*)(cmb + CSTR + base);
        ushort8 c2 = *(const ushort8*)(cmb + 2 * (size_t)CSTR + base);
        #pragma unroll
        for (int e = 0; e < 8; ++e)
            cs[n][g + e] = bf2f(c0[e]) + bf2f(c1[e]) + bf2f(c2[e]);
    }
    __syncthreads();

    int nq = (t & 15) * 4;
    int cg = t >> 4;
    int c0i = cq * 64 + cg * 4;
    float acc[4][4];
    #pragma unroll
    for (int a = 0; a < 4; ++a)
        #pragma unroll
        for (int bb2 = 0; bb2 < 4; ++bb2) acc[a][bb2] = 0.f;

    for (int g = 0; g < 192; g += 4) {
        float4 w0 = *(const float4*)(wo + (c0i + 0) * 192 + g);
        float4 w1 = *(const float4*)(wo + (c0i + 1) * 192 + g);
        float4 w2 = *(const float4*)(wo + (c0i + 2) * 192 + g);
        float4 w3 = *(const float4*)(wo + (c0i + 3) * 192 + g);
        #pragma unroll
        for (int nn = 0; nn < 4; ++nn) {
            float4 cv = *(const float4*)&cs[nq + nn][g];
            acc[0][nn] += w0.x * cv.x + w0.y * cv.y + w0.z * cv.z + w0.w * cv.w;
            acc[1][nn] += w1.x * cv.x + w1.y * cv.y + w1.z * cv.z + w1.w * cv.w;
            acc[2][nn] += w2.x * cv.x + w2.y * cv.y + w2.z * cv.z + w2.w * cv.w;
            acc[3][nn] += w3.x * cv.x + w3.y * cv.y + w3.z * cv.z + w3.w * cv.w;
        }
    }
    #pragma unroll
    for (int ci = 0; ci < 4; ++ci) {
        int c = c0i + ci;
        const float* xr = x + ((size_t)(b * CC + c)) * NN_ + n0 + nq;
        float* orow = out + ((size_t)(b * CC + c)) * NN_ + n0 + nq;
        #pragma unroll
        for (int nn = 0; nn < 4; ++nn) {
            float sg = 1.f / (1.f + __expf(-acc[ci][nn]));
            orow[nn] = xr[nn] * sg;
        }
    }
}

extern "C" void kernel_launch(void* const* d_in, const int* in_sizes, int n_in,
                              void* d_out, int out_size, void* d_ws, size_t ws_size,
                              hipStream_t stream) {
    const float* x  = (const float*)d_in[0];
    const float* wq = (const float*)d_in[1];
    const float* wk = (const float*)d_in[2];
    const float* wv = (const float*)d_in[3];
    const float* wo = (const float*)d_in[4];
    unsigned short* wsb = (unsigned short*)d_ws;
    float* out = (float*)d_out;

    prep_kernel<<<297, 256, 0, stream>>>(x, wq, wk, wv, wsb);
    proj_mfma<<<648, 256, 0, stream>>>(wsb);
    attn_kernel<<<1296, 256, 0, stream>>>(wsb);
    out_kernel<<<576, 256, 0, stream>>>(x, wo, wsb, out);
}

// Round 9
// 132.926 us; speedup vs baseline: 3.5815x; 3.5815x over previous
//
#include <hip/hip_runtime.h>

// NestedAttention MI355X round 9: key-split TLP (round-8 structure) with a
// register-feasible budget: launch_bounds(256,4) (VGPR cap 128), ones-MFMA
// lacc replaced by scalar VALU l (saves 16 VGPR -> no spill).
//
// ws layout (ushort elems):
//   Qf  [3i][4b][72 t][4 f][512]   @ OQ    (frag chunks, == Kf layout)
//   Kf  [3i][4b][72 t][4 f][512]   @ OK_
//   Vf  [3i][4b][72 t][2c][2rb][512] @ OV
//   combj [3j][4b][N][192g]        @ OC (+j*CSTR)
//   xf  [4b][72 nb][16 ks][512]    @ OXF   (x as B-frag chunks, bf16)
//   Wf  [9 s][16 ks][2 rb][512]    @ OWF   (weights as A-frag chunks)
// Frag chunk: chunk[lane*8+e] = Op[idx=lane&31][k=8*(lane>>5)+e]

#define BB 4
#define CC 256
#define NN_ 2304
#define RR 64

#define OQ 0
#define OK_ 1769472
#define OV 3538944
#define OC 5308416
#define CSTR 1769472
#define FR_IB 147456   // per (i,b) frag-buffer stride (= N*64)
#define OXF 10616832
#define OWF 12976128

typedef __bf16 bf16x8 __attribute__((ext_vector_type(8)));
typedef float f32x16 __attribute__((ext_vector_type(16)));
typedef unsigned short ushort8 __attribute__((ext_vector_type(8)));
typedef unsigned int uintx2 __attribute__((ext_vector_type(2)));
typedef unsigned int uintx4 __attribute__((ext_vector_type(4)));

__device__ __forceinline__ unsigned short f2bf(float f) {
    unsigned int u = __builtin_bit_cast(unsigned int, f);
    u = (u + 0x7FFFu + ((u >> 16) & 1u)) >> 16;
    return (unsigned short)u;
}
__device__ __forceinline__ float bf2f(unsigned short s) {
    unsigned int u = ((unsigned int)s) << 16;
    return __builtin_bit_cast(float, u);
}
__device__ __forceinline__ unsigned int pk_bf16(float lo, float hi) {
    unsigned int r;
    asm("v_cvt_pk_bf16_f32 %0, %1, %2" : "=v"(r) : "v"(lo), "v"(hi));
    return r;
}

// ---------------------------------------------------------------------------
// Prep (merged): bid<9 -> weights to A-frag chunks; else x to B-frag chunks.
// ---------------------------------------------------------------------------
__global__ __launch_bounds__(256) void prep_kernel(
    const float* __restrict__ x, const float* __restrict__ wq,
    const float* __restrict__ wk, const float* __restrict__ wv,
    unsigned short* __restrict__ wsb)
{
    int bid = blockIdx.x;
    int t = threadIdx.x;
    if (bid < 9) {
        int s = bid;
        int type = s / 3, i = s % 3;
        const float* wsel = (type == 0) ? wq : (type == 1 ? wk : wv);
        const float scale = (type == 0) ? 0.18033688011112042f : 1.0f;  // 0.125*log2e
        unsigned short* dst = wsb + OWF + s * 16384;
        #pragma unroll
        for (int p = 0; p < 8; ++p) {
            int u = t + 256 * p;
            int ks = u >> 7, rb = (u >> 6) & 1, lo = u & 63;
            int row = rb * 32 + (lo & 31), c = ks * 16 + 8 * (lo >> 5);
            const float* src = wsel + ((i * 64 + row) * 256 + c);
            float4 f0 = *(const float4*)(src);
            float4 f1 = *(const float4*)(src + 4);
            uintx4 pwv = {pk_bf16(f0.x * scale, f0.y * scale),
                          pk_bf16(f0.z * scale, f0.w * scale),
                          pk_bf16(f1.x * scale, f1.y * scale),
                          pk_bf16(f1.z * scale, f1.w * scale)};
            *(uintx4*)(dst + (ks * 2 + rb) * 512 + lo * 8) = pwv;
        }
        return;
    }
    __shared__ __align__(16) float xs[64 * 132];
    int xb = bid - 9;
    int cq  = xb & 3;
    int nt2 = (xb >> 2) % 18;
    int b   = xb / 72;
    int c0 = cq * 64, n0 = nt2 * 128;
    #pragma unroll
    for (int p = 0; p < 8; ++p) {
        int u = t + 256 * p;
        int cl = u >> 5, nq = (u & 31) * 4;
        *(float4*)&xs[cl * 132 + nq] =
            *(const float4*)&x[((size_t)(b * CC + c0 + cl)) * NN_ + n0 + nq];
    }
    __syncthreads();
    unsigned short* xfb = wsb + OXF + ((size_t)b) * 72 * 16 * 512;
    #pragma unroll
    for (int p = 0; p < 4; ++p) {
        int u = t + 256 * p;
        int nb_l = u >> 8, ks_l = (u >> 6) & 3, lo = u & 63;
        int hh = lo >> 5, idx = lo & 31;
        int clb = ks_l * 16 + 8 * hh;
        int nn = nb_l * 32 + idx;
        unsigned int pw[4];
        #pragma unroll
        for (int d = 0; d < 4; ++d) {
            float a  = xs[(clb + 2 * d) * 132 + nn];
            float bb = xs[(clb + 2 * d + 1) * 132 + nn];
            pw[d] = pk_bf16(a, bb);
        }
        int nb = nt2 * 4 + nb_l, ks = cq * 4 + ks_l;
        *(uintx4*)(xfb + (nb * 16 + ks) * 512 + lo * 8) =
            (uintx4){pw[0], pw[1], pw[2], pw[3]};
    }
}

// ---------------------------------------------------------------------------
// Kernel: MFMA projection (unchanged structure).
// ---------------------------------------------------------------------------
__global__ __launch_bounds__(256) void proj_mfma(unsigned short* __restrict__ wsb)
{
    int bid = blockIdx.x;
    int s = bid / 72;
    int rem = bid % 72;
    int b = rem / 18, nb4 = rem % 18;
    int type = s / 3, i = s % 3;
    int t = threadIdx.x;
    int w = t >> 6, lane = t & 63;
    int lq = lane & 31, h = lane >> 5;
    int nb = nb4 * 4 + w;

    const unsigned short* wf = wsb + OWF + s * 16384 + lane * 8;
    const unsigned short* xf = wsb + OXF + ((size_t)(b * 72 + nb) * 16) * 512 + lane * 8;

    f32x16 o0 = {}, o1 = {};
    if (type < 2) {
        #pragma unroll
        for (int ks = 0; ks < 16; ++ks) {
            bf16x8 a0 = *(const bf16x8*)(wf + ks * 1024);
            bf16x8 a1 = *(const bf16x8*)(wf + ks * 1024 + 512);
            bf16x8 bx = *(const bf16x8*)(xf + ks * 512);
            o0 = __builtin_amdgcn_mfma_f32_32x32x16_bf16(a0, bx, o0, 0, 0, 0);
            o1 = __builtin_amdgcn_mfma_f32_32x32x16_bf16(a1, bx, o1, 0, 0, 0);
        }
    } else {
        #pragma unroll
        for (int ks = 0; ks < 16; ++ks) {
            bf16x8 a0 = *(const bf16x8*)(wf + ks * 1024);
            bf16x8 a1 = *(const bf16x8*)(wf + ks * 1024 + 512);
            bf16x8 bx = *(const bf16x8*)(xf + ks * 512);
            o0 = __builtin_amdgcn_mfma_f32_32x32x16_bf16(bx, a0, o0, 0, 0, 0);
            o1 = __builtin_amdgcn_mfma_f32_32x32x16_bf16(bx, a1, o1, 0, 0, 0);
        }
    }

    unsigned short* dstbase =
        wsb + ((type == 0) ? OQ : (type == 1 ? OK_ : OV)) +
        ((size_t)(i * 4 + b)) * FR_IB + nb * 2048;

    if (type < 2) {
        #pragma unroll
        for (int g = 0; g < 4; ++g) {
            int kd = 8 * g + 4 * h;
            int off = (kd >> 4) * 512 + ((kd >> 3) & 1) * 256 + lq * 8 + (kd & 7);
            *(uintx2*)(dstbase + off) =
                (uintx2){pk_bf16(o0[4 * g], o0[4 * g + 1]),
                         pk_bf16(o0[4 * g + 2], o0[4 * g + 3])};
            int kd2 = kd + 32;
            int off2 = (kd2 >> 4) * 512 + ((kd2 >> 3) & 1) * 256 + lq * 8 + (kd2 & 7);
            *(uintx2*)(dstbase + off2) =
                (uintx2){pk_bf16(o1[4 * g], o1[4 * g + 1]),
                         pk_bf16(o1[4 * g + 2], o1[4 * g + 3])};
        }
    } else {
        #pragma unroll
        for (int g = 0; g < 4; ++g) {
            int off = (g >> 1) * 1024 + (g & 1) * 256 + lq * 8 + 4 * h;
            *(uintx2*)(dstbase + off) =
                (uintx2){pk_bf16(o0[4 * g], o0[4 * g + 1]),
                         pk_bf16(o0[4 * g + 2], o0[4 * g + 3])};
            *(uintx2*)(dstbase + off + 512) =
                (uintx2){pk_bf16(o1[4 * g], o1[4 * g + 1]),
                         pk_bf16(o1[4 * g + 2], o1[4 * g + 3])};
        }
    }
}

// ---------------------------------------------------------------------------
// Kernel: MFMA flash attention, key-split. Block = 4 waves (256 thr):
// wave w -> ks = w&1 (key half), qloc = w>>1 (q-tile). Two LDS streams
// (one per ks), each double-buffered 2x8KB, shared by the 2 q-tile waves.
// l tracked as per-half VALU scalar (no lacc MFMA; -16 VGPR).
// Epilogue: ks1 posts (O,l) to LDS; ks0 combines, normalizes, stores.
// ---------------------------------------------------------------------------
__global__ __launch_bounds__(256, 4) void attn_kernel(unsigned short* __restrict__ wsb)
{
    __shared__ __align__(16) unsigned char lds_raw[32768];
    unsigned short* kvbuf = (unsigned short*)lds_raw;  // [2 ks][2 buf][4096]
    float* fl = (float*)lds_raw;                       // epilogue reuse

    int bid = blockIdx.x;
    int wid = (bid & 7) * 162 + (bid >> 3);   // XCD-contiguous (1296 = 8*162)
    int s12 = wid / 108;                      // (j,b) reuse set
    int rem = wid % 108;
    int j = s12 >> 2, b = s12 & 3;
    int i = rem / 36;
    int qp = rem % 36;
    int w = threadIdx.x >> 6;
    int ks = w & 1, qloc = w >> 1;
    int lane = threadIdx.x & 63;
    int lq = lane & 31;
    int h = lane >> 5;
    int q0 = (qp * 2 + qloc) * 32;

    const unsigned short* qtf = wsb + OQ + ((size_t)(i * 4 + b)) * FR_IB +
                                (q0 >> 5) * 2048 + lane * 8;
    const unsigned short* kf = wsb + OK_ + ((size_t)(j * 4 + b)) * FR_IB;
    const unsigned short* vf = wsb + OV + ((size_t)(j * 4 + b)) * FR_IB;

    bf16x8 bq0 = *(const bf16x8*)(qtf + 0);
    bf16x8 bq1 = *(const bf16x8*)(qtf + 512);
    bf16x8 bq2 = *(const bf16x8*)(qtf + 1024);
    bf16x8 bq3 = *(const bf16x8*)(qtf + 1536);

    // staging: within stream ks, wave qloc0 stages K chunks (slots 0-3),
    // qloc1 stages V chunks (slots 4-7). 36 tiles starting at ks*36.
    const unsigned short* sbase =
        ((qloc == 0) ? kf : vf) + (size_t)(ks * 36) * 2048 + lane * 8;
    int dbase = ks * 8192 + qloc * 2048 + lane * 8;
    int sread = ks * 8192;

    f32x16 o0 = {}, o1 = {};
    float l_loc = 0.f;

    auto compute_step = [&](const unsigned short* base) {
        bf16x8 k0 = *(const bf16x8*)(base + 0 * 512 + lane * 8);
        bf16x8 k1 = *(const bf16x8*)(base + 1 * 512 + lane * 8);
        bf16x8 k2 = *(const bf16x8*)(base + 2 * 512 + lane * 8);
        bf16x8 k3 = *(const bf16x8*)(base + 3 * 512 + lane * 8);
        bf16x8 v00 = *(const bf16x8*)(base + 4 * 512 + lane * 8);  // c0,rb0
        bf16x8 v10 = *(const bf16x8*)(base + 5 * 512 + lane * 8);  // c0,rb1
        bf16x8 v01 = *(const bf16x8*)(base + 6 * 512 + lane * 8);  // c1,rb0
        bf16x8 v11 = *(const bf16x8*)(base + 7 * 512 + lane * 8);  // c1,rb1

        f32x16 s = {};
        __builtin_amdgcn_s_setprio(1);
        s = __builtin_amdgcn_mfma_f32_32x32x16_bf16(k0, bq0, s, 0, 0, 0);
        s = __builtin_amdgcn_mfma_f32_32x32x16_bf16(k1, bq1, s, 0, 0, 0);
        s = __builtin_amdgcn_mfma_f32_32x32x16_bf16(k2, bq2, s, 0, 0, 0);
        s = __builtin_amdgcn_mfma_f32_32x32x16_bf16(k3, bq3, s, 0, 0, 0);
        __builtin_amdgcn_s_setprio(0);

        // raw exp2 — no max subtraction (|S|log2e bounded ~12 by input norms)
        #pragma unroll
        for (int r = 0; r < 16; ++r) s[r] = exp2f(s[r]);
        // per-half l partial (merged cross-half at epilogue)
        float tsum = ((s[0] + s[1]) + (s[2] + s[3])) + ((s[4] + s[5]) + (s[6] + s[7])) +
                     ((s[8] + s[9]) + (s[10] + s[11])) + ((s[12] + s[13]) + (s[14] + s[15]));
        l_loc += tsum;

        __builtin_amdgcn_s_setprio(1);
        {   // keys 0..15 of this 32-key step
            unsigned int a0 = pk_bf16(s[0], s[1]);
            unsigned int a1 = pk_bf16(s[2], s[3]);
            unsigned int b0 = pk_bf16(s[4], s[5]);
            unsigned int b1 = pk_bf16(s[6], s[7]);
            uintx2 r0 = __builtin_amdgcn_permlane32_swap(a0, b0, false, false);
            uintx2 r1 = __builtin_amdgcn_permlane32_swap(a1, b1, false, false);
            uintx4 pwv = {r0[0], r1[0], r0[1], r1[1]};
            bf16x8 pa = __builtin_bit_cast(bf16x8, pwv);
            o0 = __builtin_amdgcn_mfma_f32_32x32x16_bf16(v00, pa, o0, 0, 0, 0);
            o1 = __builtin_amdgcn_mfma_f32_32x32x16_bf16(v10, pa, o1, 0, 0, 0);
        }
        {   // keys 16..31
            unsigned int a0 = pk_bf16(s[8], s[9]);
            unsigned int a1 = pk_bf16(s[10], s[11]);
            unsigned int b0 = pk_bf16(s[12], s[13]);
            unsigned int b1 = pk_bf16(s[14], s[15]);
            uintx2 r0 = __builtin_amdgcn_permlane32_swap(a0, b0, false, false);
            uintx2 r1 = __builtin_amdgcn_permlane32_swap(a1, b1, false, false);
            uintx4 pwv = {r0[0], r1[0], r0[1], r1[1]};
            bf16x8 pa = __builtin_bit_cast(bf16x8, pwv);
            o0 = __builtin_amdgcn_mfma_f32_32x32x16_bf16(v01, pa, o0, 0, 0, 0);
            o1 = __builtin_amdgcn_mfma_f32_32x32x16_bf16(v11, pa, o1, 0, 0, 0);
        }
        __builtin_amdgcn_s_setprio(0);
    };

    // ---- prologue: stage step 0, prefetch step 1 ----
    ushort8 pre0 = *(const ushort8*)(sbase + 0 * 512);
    ushort8 pre1 = *(const ushort8*)(sbase + 1 * 512);
    ushort8 pre2 = *(const ushort8*)(sbase + 2 * 512);
    ushort8 pre3 = *(const ushort8*)(sbase + 3 * 512);
    *(ushort8*)(kvbuf + dbase + 0 * 512) = pre0;
    *(ushort8*)(kvbuf + dbase + 1 * 512) = pre1;
    *(ushort8*)(kvbuf + dbase + 2 * 512) = pre2;
    *(ushort8*)(kvbuf + dbase + 3 * 512) = pre3;
    pre0 = *(const ushort8*)(sbase + 2048 + 0 * 512);
    pre1 = *(const ushort8*)(sbase + 2048 + 1 * 512);
    pre2 = *(const ushort8*)(sbase + 2048 + 2 * 512);
    pre3 = *(const ushort8*)(sbase + 2048 + 3 * 512);
    __syncthreads();

    int cur = 0;
    for (int step = 0; step < 36; ++step) {
        if (step + 1 < 36) {   // write prefetched step+1 into other buffer
            unsigned short* wb = kvbuf + dbase + (cur ^ 1) * 4096;
            *(ushort8*)(wb + 0 * 512) = pre0;
            *(ushort8*)(wb + 1 * 512) = pre1;
            *(ushort8*)(wb + 2 * 512) = pre2;
            *(ushort8*)(wb + 3 * 512) = pre3;
        }
        if (step + 2 < 36) {   // issue loads for step+2
            const unsigned short* sp = sbase + (step + 2) * 2048;
            pre0 = *(const ushort8*)(sp + 0 * 512);
            pre1 = *(const ushort8*)(sp + 1 * 512);
            pre2 = *(const ushort8*)(sp + 2 * 512);
            pre3 = *(const ushort8*)(sp + 3 * 512);
        }
        compute_step(kvbuf + sread + cur * 4096);
        __syncthreads();
        cur ^= 1;
    }

    // full l for this wave (both key-half lanes of own 1152-key range)
    float l_full = l_loc + __shfl_xor(l_loc, 32);

    // ---- combine ks halves: O = (O0+O1)/(l0+l1) ----
    int off = qloc * 2112;
    if (ks == 1) {
        #pragma unroll
        for (int reg = 0; reg < 16; ++reg) {
            fl[off + reg * 64 + lane] = o0[reg];
            fl[off + 1024 + reg * 64 + lane] = o1[reg];
        }
        fl[off + 2048 + lane] = l_full;
    }
    __syncthreads();
    if (ks == 1) return;

    #pragma unroll
    for (int reg = 0; reg < 16; ++reg) {
        o0[reg] += fl[off + reg * 64 + lane];
        o1[reg] += fl[off + 1024 + reg * 64 + lane];
    }
    float l_tot = l_full + fl[off + 2048 + lane];
    __syncthreads();   // fl region now reusable for transpose

    float inv = 1.f / l_tot;
    o0 *= inv; o1 *= inv;

    // transpose O^T (rows r_v, col=own q) -> comb rows [n][g] via LDS
    float* tw = fl + qloc * 2080;
    #pragma unroll
    for (int reg = 0; reg < 16; ++reg) {
        int rv = (reg & 3) + 8 * (reg >> 2) + 4 * h;
        tw[lq * 65 + rv] = o0[reg];
        tw[lq * 65 + 32 + rv] = o1[reg];
    }
    int q = lane >> 1, half = lane & 1;
    unsigned int pw[16];
    #pragma unroll
    for (int d = 0; d < 16; ++d) {
        float a = tw[q * 65 + half * 32 + 2 * d];
        float bv = tw[q * 65 + half * 32 + 2 * d + 1];
        pw[d] = (unsigned int)f2bf(a) | ((unsigned int)f2bf(bv) << 16);
    }
    unsigned int* dstp = (unsigned int*)(wsb + OC + (size_t)j * CSTR +
                        ((size_t)(b * NN_ + q0 + q)) * 192 + i * 64 + half * 32);
    #pragma unroll
    for (int t4 = 0; t4 < 4; ++t4)
        *(uintx4*)(dstp + t4 * 4) = (uintx4){pw[4 * t4], pw[4 * t4 + 1], pw[4 * t4 + 2], pw[4 * t4 + 3]};
}

// ---------------------------------------------------------------------------
// Kernel: out[b,c,n] = sum_g wo[c,g] * (sum_j combj[b,n,g]); y = x*sigmoid.
// ---------------------------------------------------------------------------
__global__ __launch_bounds__(256) void out_kernel(
    const float* __restrict__ x, const float* __restrict__ wo,
    const unsigned short* __restrict__ wsb, float* __restrict__ out)
{
    __shared__ __align__(16) float cs[64][196];
    int bid  = blockIdx.x;
    int cq   = bid & 3;
    int tile = (bid >> 2) % 36;
    int b    = bid / 144;
    int n0   = tile * 64;
    int t    = threadIdx.x;

    const unsigned short* cmb = wsb + OC;
    for (int u = t * 8; u < 64 * 192; u += 256 * 8) {
        int n = u / 192, g = u % 192;
        size_t base = ((size_t)(b * NN_ + n0 + n)) * 192 + g;
        ushort8 c0 = *(const ushort8*)(cmb + base);
        ushort8 c1 = *(const ushort8*)(cmb + CSTR + base);
        ushort8 c2 = *(const ushort8*)(cmb + 2 * (size_t)CSTR + base);
        #pragma unroll
        for (int e = 0; e < 8; ++e)
            cs[n][g + e] = bf2f(c0[e]) + bf2f(c1[e]) + bf2f(c2[e]);
    }
    __syncthreads();

    int nq = (t & 15) * 4;
    int cg = t >> 4;
    int c0i = cq * 64 + cg * 4;
    float acc[4][4];
    #pragma unroll
    for (int a = 0; a < 4; ++a)
        #pragma unroll
        for (int bb2 = 0; bb2 < 4; ++bb2) acc[a][bb2] = 0.f;

    for (int g = 0; g < 192; g += 4) {
        float4 w0 = *(const float4*)(wo + (c0i + 0) * 192 + g);
        float4 w1 = *(const float4*)(wo + (c0i + 1) * 192 + g);
        float4 w2 = *(const float4*)(wo + (c0i + 2) * 192 + g);
        float4 w3 = *(const float4*)(wo + (c0i + 3) * 192 + g);
        #pragma unroll
        for (int nn = 0; nn < 4; ++nn) {
            float4 cv = *(const float4*)&cs[nq + nn][g];
            acc[0][nn] += w0.x * cv.x + w0.y * cv.y + w0.z * cv.z + w0.w * cv.w;
            acc[1][nn] += w1.x * cv.x + w1.y * cv.y + w1.z * cv.z + w1.w * cv.w;
            acc[2][nn] += w2.x * cv.x + w2.y * cv.y + w2.z * cv.z + w2.w * cv.w;
            acc[3][nn] += w3.x * cv.x + w3.y * cv.y + w3.z * cv.z + w3.w * cv.w;
        }
    }
    #pragma unroll
    for (int ci = 0; ci < 4; ++ci) {
        int c = c0i + ci;
        const float* xr = x + ((size_t)(b * CC + c)) * NN_ + n0 + nq;
        float* orow = out + ((size_t)(b * CC + c)) * NN_ + n0 + nq;
        #pragma unroll
        for (int nn = 0; nn < 4; ++nn) {
            float sg = 1.f / (1.f + __expf(-acc[ci][nn]));
            orow[nn] = xr[nn] * sg;
        }
    }
}

extern "C" void kernel_launch(void* const* d_in, const int* in_sizes, int n_in,
                              void* d_out, int out_size, void* d_ws, size_t ws_size,
                              hipStream_t stream) {
    const float* x  = (const float*)d_in[0];
    const float* wq = (const float*)d_in[1];
    const float* wk = (const float*)d_in[2];
    const float* wv = (const float*)d_in[3];
    const float* wo = (const float*)d_in[4];
    unsigned short* wsb = (unsigned short*)d_ws;
    float* out = (float*)d_out;

    prep_kernel<<<297, 256, 0, stream>>>(x, wq, wk, wv, wsb);
    proj_mfma<<<648, 256, 0, stream>>>(wsb);
    attn_kernel<<<1296, 256, 0, stream>>>(wsb);
    out_kernel<<<576, 256, 0, stream>>>(x, wo, wsb, out);
}

// Round 10
// 118.561 us; speedup vs baseline: 4.0154x; 1.1212x over previous
//
#include <hip/hip_runtime.h>

// NestedAttention MI355X round 10: VALU diet for attn — raw v_exp_f32
// (no libm range fixup; |S|log2e <= ~12), global_load_lds staging
// (no reg round-trip), l via ones-MFMA (no add-tree, no shuffles).
// Structure = round 9 key-split: block = 4 waves = 2 q-tiles x 2 key-halves.
//
// ws layout (ushort elems):
//   Qf  [3i][4b][72 t][4 f][512]   @ OQ    (frag chunks, == Kf layout)
//   Kf  [3i][4b][72 t][4 f][512]   @ OK_
//   Vf  [3i][4b][72 t][2c][2rb][512] @ OV
//   combj [3j][4b][N][192g]        @ OC (+j*CSTR)
//   xf  [4b][72 nb][16 ks][512]    @ OXF   (x as B-frag chunks, bf16)
//   Wf  [9 s][16 ks][2 rb][512]    @ OWF   (weights as A-frag chunks)
// Frag chunk: chunk[lane*8+e] = Op[idx=lane&31][k=8*(lane>>5)+e]

#define BB 4
#define CC 256
#define NN_ 2304
#define RR 64

#define OQ 0
#define OK_ 1769472
#define OV 3538944
#define OC 5308416
#define CSTR 1769472
#define FR_IB 147456   // per (i,b) frag-buffer stride (= N*64)
#define OXF 10616832
#define OWF 12976128

typedef __bf16 bf16x8 __attribute__((ext_vector_type(8)));
typedef float f32x16 __attribute__((ext_vector_type(16)));
typedef unsigned short ushort8 __attribute__((ext_vector_type(8)));
typedef unsigned int uintx2 __attribute__((ext_vector_type(2)));
typedef unsigned int uintx4 __attribute__((ext_vector_type(4)));

#if __has_builtin(__builtin_amdgcn_exp2f)
#define EXP2(x) __builtin_amdgcn_exp2f(x)
#else
#define EXP2(x) exp2f(x)
#endif

__device__ __forceinline__ unsigned short f2bf(float f) {
    unsigned int u = __builtin_bit_cast(unsigned int, f);
    u = (u + 0x7FFFu + ((u >> 16) & 1u)) >> 16;
    return (unsigned short)u;
}
__device__ __forceinline__ float bf2f(unsigned short s) {
    unsigned int u = ((unsigned int)s) << 16;
    return __builtin_bit_cast(float, u);
}
__device__ __forceinline__ unsigned int pk_bf16(float lo, float hi) {
    unsigned int r;
    asm("v_cvt_pk_bf16_f32 %0, %1, %2" : "=v"(r) : "v"(lo), "v"(hi));
    return r;
}
// async 16B/lane global->LDS DMA; lds dst is wave-uniform base (+lane*16 by HW)
__device__ __forceinline__ void gload16(const unsigned short* g, unsigned short* l) {
    __builtin_amdgcn_global_load_lds(
        (const __attribute__((address_space(1))) unsigned int*)(g),
        (__attribute__((address_space(3))) unsigned int*)(l),
        16, 0, 0);
}

// ---------------------------------------------------------------------------
// Prep (merged): bid<9 -> weights to A-frag chunks; else x to B-frag chunks.
// ---------------------------------------------------------------------------
__global__ __launch_bounds__(256) void prep_kernel(
    const float* __restrict__ x, const float* __restrict__ wq,
    const float* __restrict__ wk, const float* __restrict__ wv,
    unsigned short* __restrict__ wsb)
{
    int bid = blockIdx.x;
    int t = threadIdx.x;
    if (bid < 9) {
        int s = bid;
        int type = s / 3, i = s % 3;
        const float* wsel = (type == 0) ? wq : (type == 1 ? wk : wv);
        const float scale = (type == 0) ? 0.18033688011112042f : 1.0f;  // 0.125*log2e
        unsigned short* dst = wsb + OWF + s * 16384;
        #pragma unroll
        for (int p = 0; p < 8; ++p) {
            int u = t + 256 * p;
            int ks = u >> 7, rb = (u >> 6) & 1, lo = u & 63;
            int row = rb * 32 + (lo & 31), c = ks * 16 + 8 * (lo >> 5);
            const float* src = wsel + ((i * 64 + row) * 256 + c);
            float4 f0 = *(const float4*)(src);
            float4 f1 = *(const float4*)(src + 4);
            uintx4 pwv = {pk_bf16(f0.x * scale, f0.y * scale),
                          pk_bf16(f0.z * scale, f0.w * scale),
                          pk_bf16(f1.x * scale, f1.y * scale),
                          pk_bf16(f1.z * scale, f1.w * scale)};
            *(uintx4*)(dst + (ks * 2 + rb) * 512 + lo * 8) = pwv;
        }
        return;
    }
    __shared__ __align__(16) float xs[64 * 132];
    int xb = bid - 9;
    int cq  = xb & 3;
    int nt2 = (xb >> 2) % 18;
    int b   = xb / 72;
    int c0 = cq * 64, n0 = nt2 * 128;
    #pragma unroll
    for (int p = 0; p < 8; ++p) {
        int u = t + 256 * p;
        int cl = u >> 5, nq = (u & 31) * 4;
        *(float4*)&xs[cl * 132 + nq] =
            *(const float4*)&x[((size_t)(b * CC + c0 + cl)) * NN_ + n0 + nq];
    }
    __syncthreads();
    unsigned short* xfb = wsb + OXF + ((size_t)b) * 72 * 16 * 512;
    #pragma unroll
    for (int p = 0; p < 4; ++p) {
        int u = t + 256 * p;
        int nb_l = u >> 8, ks_l = (u >> 6) & 3, lo = u & 63;
        int hh = lo >> 5, idx = lo & 31;
        int clb = ks_l * 16 + 8 * hh;
        int nn = nb_l * 32 + idx;
        unsigned int pw[4];
        #pragma unroll
        for (int d = 0; d < 4; ++d) {
            float a  = xs[(clb + 2 * d) * 132 + nn];
            float bb = xs[(clb + 2 * d + 1) * 132 + nn];
            pw[d] = pk_bf16(a, bb);
        }
        int nb = nt2 * 4 + nb_l, ks = cq * 4 + ks_l;
        *(uintx4*)(xfb + (nb * 16 + ks) * 512 + lo * 8) =
            (uintx4){pw[0], pw[1], pw[2], pw[3]};
    }
}

// ---------------------------------------------------------------------------
// Kernel: MFMA projection (unchanged structure).
// ---------------------------------------------------------------------------
__global__ __launch_bounds__(256) void proj_mfma(unsigned short* __restrict__ wsb)
{
    int bid = blockIdx.x;
    int s = bid / 72;
    int rem = bid % 72;
    int b = rem / 18, nb4 = rem % 18;
    int type = s / 3, i = s % 3;
    int t = threadIdx.x;
    int w = t >> 6, lane = t & 63;
    int lq = lane & 31, h = lane >> 5;
    int nb = nb4 * 4 + w;

    const unsigned short* wf = wsb + OWF + s * 16384 + lane * 8;
    const unsigned short* xf = wsb + OXF + ((size_t)(b * 72 + nb) * 16) * 512 + lane * 8;

    f32x16 o0 = {}, o1 = {};
    if (type < 2) {
        #pragma unroll
        for (int ks = 0; ks < 16; ++ks) {
            bf16x8 a0 = *(const bf16x8*)(wf + ks * 1024);
            bf16x8 a1 = *(const bf16x8*)(wf + ks * 1024 + 512);
            bf16x8 bx = *(const bf16x8*)(xf + ks * 512);
            o0 = __builtin_amdgcn_mfma_f32_32x32x16_bf16(a0, bx, o0, 0, 0, 0);
            o1 = __builtin_amdgcn_mfma_f32_32x32x16_bf16(a1, bx, o1, 0, 0, 0);
        }
    } else {
        #pragma unroll
        for (int ks = 0; ks < 16; ++ks) {
            bf16x8 a0 = *(const bf16x8*)(wf + ks * 1024);
            bf16x8 a1 = *(const bf16x8*)(wf + ks * 1024 + 512);
            bf16x8 bx = *(const bf16x8*)(xf + ks * 512);
            o0 = __builtin_amdgcn_mfma_f32_32x32x16_bf16(bx, a0, o0, 0, 0, 0);
            o1 = __builtin_amdgcn_mfma_f32_32x32x16_bf16(bx, a1, o1, 0, 0, 0);
        }
    }

    unsigned short* dstbase =
        wsb + ((type == 0) ? OQ : (type == 1 ? OK_ : OV)) +
        ((size_t)(i * 4 + b)) * FR_IB + nb * 2048;

    if (type < 2) {
        #pragma unroll
        for (int g = 0; g < 4; ++g) {
            int kd = 8 * g + 4 * h;
            int off = (kd >> 4) * 512 + ((kd >> 3) & 1) * 256 + lq * 8 + (kd & 7);
            *(uintx2*)(dstbase + off) =
                (uintx2){pk_bf16(o0[4 * g], o0[4 * g + 1]),
                         pk_bf16(o0[4 * g + 2], o0[4 * g + 3])};
            int kd2 = kd + 32;
            int off2 = (kd2 >> 4) * 512 + ((kd2 >> 3) & 1) * 256 + lq * 8 + (kd2 & 7);
            *(uintx2*)(dstbase + off2) =
                (uintx2){pk_bf16(o1[4 * g], o1[4 * g + 1]),
                         pk_bf16(o1[4 * g + 2], o1[4 * g + 3])};
        }
    } else {
        #pragma unroll
        for (int g = 0; g < 4; ++g) {
            int off = (g >> 1) * 1024 + (g & 1) * 256 + lq * 8 + 4 * h;
            *(uintx2*)(dstbase + off) =
                (uintx2){pk_bf16(o0[4 * g], o0[4 * g + 1]),
                         pk_bf16(o0[4 * g + 2], o0[4 * g + 3])};
            *(uintx2*)(dstbase + off + 512) =
                (uintx2){pk_bf16(o1[4 * g], o1[4 * g + 1]),
                         pk_bf16(o1[4 * g + 2], o1[4 * g + 3])};
        }
    }
}

// ---------------------------------------------------------------------------
// Kernel: MFMA flash attention, key-split + async staging.
// Block = 4 waves: wave w -> ks = w&1 (key half), qloc = w>>1 (q-tile).
// Per step: issue 4 global_load_lds for step+1 (other buffer), compute
// current from LDS, __syncthreads (drains vmcnt). l via ones-MFMA.
// Epilogue: ks1 posts (O,l) to LDS; ks0 combines, normalizes, stores.
// ---------------------------------------------------------------------------
__global__ __launch_bounds__(256, 4) void attn_kernel(unsigned short* __restrict__ wsb)
{
    __shared__ __align__(16) unsigned char lds_raw[32768];
    unsigned short* kvbuf = (unsigned short*)lds_raw;  // [2 ks][2 buf][4096]
    float* fl = (float*)lds_raw;                       // epilogue reuse

    int bid = blockIdx.x;
    int wid = (bid & 7) * 162 + (bid >> 3);   // XCD-contiguous (1296 = 8*162)
    int s12 = wid / 108;                      // (j,b) reuse set
    int rem = wid % 108;
    int j = s12 >> 2, b = s12 & 3;
    int i = rem / 36;
    int qp = rem % 36;
    int w = threadIdx.x >> 6;
    int ks = w & 1, qloc = w >> 1;
    int lane = threadIdx.x & 63;
    int lq = lane & 31;
    int h = lane >> 5;
    int q0 = (qp * 2 + qloc) * 32;

    const unsigned short* qtf = wsb + OQ + ((size_t)(i * 4 + b)) * FR_IB +
                                (q0 >> 5) * 2048 + lane * 8;
    const unsigned short* kf = wsb + OK_ + ((size_t)(j * 4 + b)) * FR_IB;
    const unsigned short* vf = wsb + OV + ((size_t)(j * 4 + b)) * FR_IB;

    bf16x8 bq0 = *(const bf16x8*)(qtf + 0);
    bf16x8 bq1 = *(const bf16x8*)(qtf + 512);
    bf16x8 bq2 = *(const bf16x8*)(qtf + 1024);
    bf16x8 bq3 = *(const bf16x8*)(qtf + 1536);

    uintx4 onesw = {0x3F803F80u, 0x3F803F80u, 0x3F803F80u, 0x3F803F80u};
    bf16x8 ones = __builtin_bit_cast(bf16x8, onesw);

    // staging: wave stages its half's K (qloc0) or V (qloc1): 4 chunks/step.
    // global src is per-lane (+lane*8); LDS dst is wave-uniform chunk base.
    const unsigned short* sbase =
        ((qloc == 0) ? kf : vf) + (size_t)(ks * 36) * 2048 + lane * 8;
    unsigned short* ldst = kvbuf + ks * 8192 + qloc * 2048;  // + buf*4096 + u*512

    f32x16 o0 = {}, o1 = {}, lacc = {};

    auto compute_step = [&](const unsigned short* base) {
        bf16x8 k0 = *(const bf16x8*)(base + 0 * 512 + lane * 8);
        bf16x8 k1 = *(const bf16x8*)(base + 1 * 512 + lane * 8);
        bf16x8 k2 = *(const bf16x8*)(base + 2 * 512 + lane * 8);
        bf16x8 k3 = *(const bf16x8*)(base + 3 * 512 + lane * 8);
        bf16x8 v00 = *(const bf16x8*)(base + 4 * 512 + lane * 8);  // c0,rb0
        bf16x8 v10 = *(const bf16x8*)(base + 5 * 512 + lane * 8);  // c0,rb1
        bf16x8 v01 = *(const bf16x8*)(base + 6 * 512 + lane * 8);  // c1,rb0
        bf16x8 v11 = *(const bf16x8*)(base + 7 * 512 + lane * 8);  // c1,rb1

        f32x16 s = {};
        __builtin_amdgcn_s_setprio(1);
        s = __builtin_amdgcn_mfma_f32_32x32x16_bf16(k0, bq0, s, 0, 0, 0);
        s = __builtin_amdgcn_mfma_f32_32x32x16_bf16(k1, bq1, s, 0, 0, 0);
        s = __builtin_amdgcn_mfma_f32_32x32x16_bf16(k2, bq2, s, 0, 0, 0);
        s = __builtin_amdgcn_mfma_f32_32x32x16_bf16(k3, bq3, s, 0, 0, 0);
        __builtin_amdgcn_s_setprio(0);

        // raw v_exp_f32 — no libm fixup (|S|log2e bounded ~12 by input norms)
        #pragma unroll
        for (int r = 0; r < 16; ++r) s[r] = EXP2(s[r]);

        __builtin_amdgcn_s_setprio(1);
        {   // keys 0..15 of this 32-key step
            unsigned int a0 = pk_bf16(s[0], s[1]);
            unsigned int a1 = pk_bf16(s[2], s[3]);
            unsigned int b0 = pk_bf16(s[4], s[5]);
            unsigned int b1 = pk_bf16(s[6], s[7]);
            uintx2 r0 = __builtin_amdgcn_permlane32_swap(a0, b0, false, false);
            uintx2 r1 = __builtin_amdgcn_permlane32_swap(a1, b1, false, false);
            uintx4 pwv = {r0[0], r1[0], r0[1], r1[1]};
            bf16x8 pa = __builtin_bit_cast(bf16x8, pwv);
            o0 = __builtin_amdgcn_mfma_f32_32x32x16_bf16(v00, pa, o0, 0, 0, 0);
            o1 = __builtin_amdgcn_mfma_f32_32x32x16_bf16(v10, pa, o1, 0, 0, 0);
            lacc = __builtin_amdgcn_mfma_f32_32x32x16_bf16(ones, pa, lacc, 0, 0, 0);
        }
        {   // keys 16..31
            unsigned int a0 = pk_bf16(s[8], s[9]);
            unsigned int a1 = pk_bf16(s[10], s[11]);
            unsigned int b0 = pk_bf16(s[12], s[13]);
            unsigned int b1 = pk_bf16(s[14], s[15]);
            uintx2 r0 = __builtin_amdgcn_permlane32_swap(a0, b0, false, false);
            uintx2 r1 = __builtin_amdgcn_permlane32_swap(a1, b1, false, false);
            uintx4 pwv = {r0[0], r1[0], r0[1], r1[1]};
            bf16x8 pa = __builtin_bit_cast(bf16x8, pwv);
            o0 = __builtin_amdgcn_mfma_f32_32x32x16_bf16(v01, pa, o0, 0, 0, 0);
            o1 = __builtin_amdgcn_mfma_f32_32x32x16_bf16(v11, pa, o1, 0, 0, 0);
            lacc = __builtin_amdgcn_mfma_f32_32x32x16_bf16(ones, pa, lacc, 0, 0, 0);
        }
        __builtin_amdgcn_s_setprio(0);
    };

    // ---- prologue: async-stage step 0 ----
    #pragma unroll
    for (int u = 0; u < 4; ++u)
        gload16(sbase + u * 512, ldst + u * 512);
    __syncthreads();   // drains vmcnt -> step 0 resident

    int cur = 0;
    for (int step = 0; step < 36; ++step) {
        if (step + 1 < 36) {   // async-stage step+1 into other buffer
            const unsigned short* sp = sbase + (size_t)(step + 1) * 2048;
            unsigned short* lp = ldst + (cur ^ 1) * 4096;
            #pragma unroll
            for (int u = 0; u < 4; ++u)
                gload16(sp + u * 512, lp + u * 512);
        }
        compute_step(kvbuf + ks * 8192 + cur * 4096);
        __syncthreads();   // waits compute readers + drains step+1 DMA
        cur ^= 1;
    }

    // full l for this wave's 1152 keys (every lane holds its query's sum)
    float l_full = lacc[0];

    // ---- combine ks halves: O = (O0+O1)/(l0+l1) ----
    int off = qloc * 2112;
    if (ks == 1) {
        #pragma unroll
        for (int reg = 0; reg < 16; ++reg) {
            fl[off + reg * 64 + lane] = o0[reg];
            fl[off + 1024 + reg * 64 + lane] = o1[reg];
        }
        fl[off + 2048 + lane] = l_full;
    }
    __syncthreads();
    if (ks == 1) return;

    #pragma unroll
    for (int reg = 0; reg < 16; ++reg) {
        o0[reg] += fl[off + reg * 64 + lane];
        o1[reg] += fl[off + 1024 + reg * 64 + lane];
    }
    float l_tot = l_full + fl[off + 2048 + lane];
    __syncthreads();   // fl region now reusable for transpose

    float inv = 1.f / l_tot;
    o0 *= inv; o1 *= inv;

    // transpose O^T (rows r_v, col=own q) -> comb rows [n][g] via LDS
    float* tw = fl + qloc * 2080;
    #pragma unroll
    for (int reg = 0; reg < 16; ++reg) {
        int rv = (reg & 3) + 8 * (reg >> 2) + 4 * h;
        tw[lq * 65 + rv] = o0[reg];
        tw[lq * 65 + 32 + rv] = o1[reg];
    }
    int q = lane >> 1, half = lane & 1;
    unsigned int pw[16];
    #pragma unroll
    for (int d = 0; d < 16; ++d) {
        float a = tw[q * 65 + half * 32 + 2 * d];
        float bv = tw[q * 65 + half * 32 + 2 * d + 1];
        pw[d] = pk_bf16(a, bv);
    }
    unsigned int* dstp = (unsigned int*)(wsb + OC + (size_t)j * CSTR +
                        ((size_t)(b * NN_ + q0 + q)) * 192 + i * 64 + half * 32);
    #pragma unroll
    for (int t4 = 0; t4 < 4; ++t4)
        *(uintx4*)(dstp + t4 * 4) = (uintx4){pw[4 * t4], pw[4 * t4 + 1], pw[4 * t4 + 2], pw[4 * t4 + 3]};
}

// ---------------------------------------------------------------------------
// Kernel: out[b,c,n] = sum_g wo[c,g] * (sum_j combj[b,n,g]); y = x*sigmoid.
// ---------------------------------------------------------------------------
__global__ __launch_bounds__(256) void out_kernel(
    const float* __restrict__ x, const float* __restrict__ wo,
    const unsigned short* __restrict__ wsb, float* __restrict__ out)
{
    __shared__ __align__(16) float cs[64][196];
    int bid  = blockIdx.x;
    int cq   = bid & 3;
    int tile = (bid >> 2) % 36;
    int b    = bid / 144;
    int n0   = tile * 64;
    int t    = threadIdx.x;

    const unsigned short* cmb = wsb + OC;
    for (int u = t * 8; u < 64 * 192; u += 256 * 8) {
        int n = u / 192, g = u % 192;
        size_t base = ((size_t)(b * NN_ + n0 + n)) * 192 + g;
        ushort8 c0 = *(const ushort8*)(cmb + base);
        ushort8 c1 = *(const ushort8*)(cmb + CSTR + base);
        ushort8 c2 = *(const ushort8*)(cmb + 2 * (size_t)CSTR + base);
        #pragma unroll
        for (int e = 0; e < 8; ++e)
            cs[n][g + e] = bf2f(c0[e]) + bf2f(c1[e]) + bf2f(c2[e]);
    }
    __syncthreads();

    int nq = (t & 15) * 4;
    int cg = t >> 4;
    int c0i = cq * 64 + cg * 4;
    float acc[4][4];
    #pragma unroll
    for (int a = 0; a < 4; ++a)
        #pragma unroll
        for (int bb2 = 0; bb2 < 4; ++bb2) acc[a][bb2] = 0.f;

    for (int g = 0; g < 192; g += 4) {
        float4 w0 = *(const float4*)(wo + (c0i + 0) * 192 + g);
        float4 w1 = *(const float4*)(wo + (c0i + 1) * 192 + g);
        float4 w2 = *(const float4*)(wo + (c0i + 2) * 192 + g);
        float4 w3 = *(const float4*)(wo + (c0i + 3) * 192 + g);
        #pragma unroll
        for (int nn = 0; nn < 4; ++nn) {
            float4 cv = *(const float4*)&cs[nq + nn][g];
            acc[0][nn] += w0.x * cv.x + w0.y * cv.y + w0.z * cv.z + w0.w * cv.w;
            acc[1][nn] += w1.x * cv.x + w1.y * cv.y + w1.z * cv.z + w1.w * cv.w;
            acc[2][nn] += w2.x * cv.x + w2.y * cv.y + w2.z * cv.z + w2.w * cv.w;
            acc[3][nn] += w3.x * cv.x + w3.y * cv.y + w3.z * cv.z + w3.w * cv.w;
        }
    }
    #pragma unroll
    for (int ci = 0; ci < 4; ++ci) {
        int c = c0i + ci;
        const float* xr = x + ((size_t)(b * CC + c)) * NN_ + n0 + nq;
        float* orow = out + ((size_t)(b * CC + c)) * NN_ + n0 + nq;
        #pragma unroll
        for (int nn = 0; nn < 4; ++nn) {
            float sg = 1.f / (1.f + __expf(-acc[ci][nn]));
            orow[nn] = xr[nn] * sg;
        }
    }
}

extern "C" void kernel_launch(void* const* d_in, const int* in_sizes, int n_in,
                              void* d_out, int out_size, void* d_ws, size_t ws_size,
                              hipStream_t stream) {
    const float* x  = (const float*)d_in[0];
    const float* wq = (const float*)d_in[1];
    const float* wk = (const float*)d_in[2];
    const float* wv = (const float*)d_in[3];
    const float* wo = (const float*)d_in[4];
    unsigned short* wsb = (unsigned short*)d_ws;
    float* out = (float*)d_out;

    prep_kernel<<<297, 256, 0, stream>>>(x, wq, wk, wv, wsb);
    proj_mfma<<<648, 256, 0, stream>>>(wsb);
    attn_kernel<<<1296, 256, 0, stream>>>(wsb);
    out_kernel<<<576, 256, 0, stream>>>(x, wo, wsb, out);
}

// Round 11
// 102.768 us; speedup vs baseline: 4.6325x; 1.1537x over previous
//
#include <hip/hip_runtime.h>

// NestedAttention MI355X round 11: barrier-free attn (direct global frag
// streams, no LDS staging, no in-loop barriers) + MFMA out-projection
// (comb written as B-frag chunks, wo packed as A-frag chunks).
//
// ws layout (ushort elems):
//   Qf  [3i][4b][72 t][4 f][512]     @ OQ
//   Kf  [3i][4b][72 t][4 f][512]     @ OK_
//   Vf  [3i][4b][72 t][2c][2rb][512] @ OV
//   combjf [3j][4b][72 nt][12 ks][512] @ OC (+j*CSTR)  (B-frag chunks)
//   xf  [4b][72 nb][16 ks][512]      @ OXF
//   Wf  [9 s][16 ks][2 rb][512]      @ OWF
//   WoF [12 ks][8 rb][512]           @ OWOF
// Frag chunk: chunk[lane*8+e] = Op[idx=lane&31][k=8*(lane>>5)+e]

#define BB 4
#define CC 256
#define NN_ 2304
#define RR 64

#define OQ 0
#define OK_ 1769472
#define OV 3538944
#define OC 5308416
#define CSTR 1769472
#define FR_IB 147456
#define OXF 10616832
#define OWF 12976128
#define OWOF 13123584

typedef __bf16 bf16x8 __attribute__((ext_vector_type(8)));
typedef float f32x16 __attribute__((ext_vector_type(16)));
typedef unsigned short ushort8 __attribute__((ext_vector_type(8)));
typedef unsigned int uintx2 __attribute__((ext_vector_type(2)));
typedef unsigned int uintx4 __attribute__((ext_vector_type(4)));

#if __has_builtin(__builtin_amdgcn_exp2f)
#define EXP2(x) __builtin_amdgcn_exp2f(x)
#else
#define EXP2(x) exp2f(x)
#endif

__device__ __forceinline__ float bf2f(unsigned short s) {
    unsigned int u = ((unsigned int)s) << 16;
    return __builtin_bit_cast(float, u);
}
__device__ __forceinline__ unsigned int pk_bf16(float lo, float hi) {
    unsigned int r;
    asm("v_cvt_pk_bf16_f32 %0, %1, %2" : "=v"(r) : "v"(lo), "v"(hi));
    return r;
}

// ---------------------------------------------------------------------------
// Prep: bid<9 weights->A-frags; bid<12 wo->A-frags; else x->B-frags.
// ---------------------------------------------------------------------------
__global__ __launch_bounds__(256) void prep_kernel(
    const float* __restrict__ x, const float* __restrict__ wq,
    const float* __restrict__ wk, const float* __restrict__ wv,
    const float* __restrict__ wo, unsigned short* __restrict__ wsb)
{
    int bid = blockIdx.x;
    int t = threadIdx.x;
    if (bid < 9) {
        int s = bid;
        int type = s / 3, i = s % 3;
        const float* wsel = (type == 0) ? wq : (type == 1 ? wk : wv);
        const float scale = (type == 0) ? 0.18033688011112042f : 1.0f;  // 0.125*log2e
        unsigned short* dst = wsb + OWF + s * 16384;
        #pragma unroll
        for (int p = 0; p < 8; ++p) {
            int u = t + 256 * p;
            int ks = u >> 7, rb = (u >> 6) & 1, lo = u & 63;
            int row = rb * 32 + (lo & 31), c = ks * 16 + 8 * (lo >> 5);
            const float* src = wsel + ((i * 64 + row) * 256 + c);
            float4 f0 = *(const float4*)(src);
            float4 f1 = *(const float4*)(src + 4);
            uintx4 pwv = {pk_bf16(f0.x * scale, f0.y * scale),
                          pk_bf16(f0.z * scale, f0.w * scale),
                          pk_bf16(f1.x * scale, f1.y * scale),
                          pk_bf16(f1.z * scale, f1.w * scale)};
            *(uintx4*)(dst + (ks * 2 + rb) * 512 + lo * 8) = pwv;
        }
        return;
    }
    if (bid < 12) {
        // wo [256][192] -> WoF chunks [ks*8+rb][512]
        int bb = bid - 9;
        #pragma unroll
        for (int p = 0; p < 8; ++p) {
            int u = t + 256 * p;
            int cg = bb * 32 + (u >> 6);          // chunk 0..95
            int lane = u & 63;
            int ks = cg >> 3, rb = cg & 7;
            int row = rb * 32 + (lane & 31);
            int g = ks * 16 + 8 * (lane >> 5);
            const float* src = wo + row * 192 + g;
            float4 f0 = *(const float4*)(src);
            float4 f1 = *(const float4*)(src + 4);
            uintx4 pwv = {pk_bf16(f0.x, f0.y), pk_bf16(f0.z, f0.w),
                          pk_bf16(f1.x, f1.y), pk_bf16(f1.z, f1.w)};
            *(uintx4*)(wsb + OWOF + cg * 512 + lane * 8) = pwv;
        }
        return;
    }
    __shared__ __align__(16) float xs[64 * 132];
    int xb = bid - 12;
    int cq  = xb & 3;
    int nt2 = (xb >> 2) % 18;
    int b   = xb / 72;
    int c0 = cq * 64, n0 = nt2 * 128;
    #pragma unroll
    for (int p = 0; p < 8; ++p) {
        int u = t + 256 * p;
        int cl = u >> 5, nq = (u & 31) * 4;
        *(float4*)&xs[cl * 132 + nq] =
            *(const float4*)&x[((size_t)(b * CC + c0 + cl)) * NN_ + n0 + nq];
    }
    __syncthreads();
    unsigned short* xfb = wsb + OXF + ((size_t)b) * 72 * 16 * 512;
    #pragma unroll
    for (int p = 0; p < 4; ++p) {
        int u = t + 256 * p;
        int nb_l = u >> 8, ks_l = (u >> 6) & 3, lo = u & 63;
        int hh = lo >> 5, idx = lo & 31;
        int clb = ks_l * 16 + 8 * hh;
        int nn = nb_l * 32 + idx;
        unsigned int pw[4];
        #pragma unroll
        for (int d = 0; d < 4; ++d) {
            float a  = xs[(clb + 2 * d) * 132 + nn];
            float bb2 = xs[(clb + 2 * d + 1) * 132 + nn];
            pw[d] = pk_bf16(a, bb2);
        }
        int nb = nt2 * 4 + nb_l, ks = cq * 4 + ks_l;
        *(uintx4*)(xfb + (nb * 16 + ks) * 512 + lo * 8) =
            (uintx4){pw[0], pw[1], pw[2], pw[3]};
    }
}

// ---------------------------------------------------------------------------
// Kernel: MFMA projection (unchanged structure).
// ---------------------------------------------------------------------------
__global__ __launch_bounds__(256) void proj_mfma(unsigned short* __restrict__ wsb)
{
    int bid = blockIdx.x;
    int s = bid / 72;
    int rem = bid % 72;
    int b = rem / 18, nb4 = rem % 18;
    int type = s / 3, i = s % 3;
    int t = threadIdx.x;
    int w = t >> 6, lane = t & 63;
    int lq = lane & 31, h = lane >> 5;
    int nb = nb4 * 4 + w;

    const unsigned short* wf = wsb + OWF + s * 16384 + lane * 8;
    const unsigned short* xf = wsb + OXF + ((size_t)(b * 72 + nb) * 16) * 512 + lane * 8;

    f32x16 o0 = {}, o1 = {};
    if (type < 2) {
        #pragma unroll
        for (int ks = 0; ks < 16; ++ks) {
            bf16x8 a0 = *(const bf16x8*)(wf + ks * 1024);
            bf16x8 a1 = *(const bf16x8*)(wf + ks * 1024 + 512);
            bf16x8 bx = *(const bf16x8*)(xf + ks * 512);
            o0 = __builtin_amdgcn_mfma_f32_32x32x16_bf16(a0, bx, o0, 0, 0, 0);
            o1 = __builtin_amdgcn_mfma_f32_32x32x16_bf16(a1, bx, o1, 0, 0, 0);
        }
    } else {
        #pragma unroll
        for (int ks = 0; ks < 16; ++ks) {
            bf16x8 a0 = *(const bf16x8*)(wf + ks * 1024);
            bf16x8 a1 = *(const bf16x8*)(wf + ks * 1024 + 512);
            bf16x8 bx = *(const bf16x8*)(xf + ks * 512);
            o0 = __builtin_amdgcn_mfma_f32_32x32x16_bf16(bx, a0, o0, 0, 0, 0);
            o1 = __builtin_amdgcn_mfma_f32_32x32x16_bf16(bx, a1, o1, 0, 0, 0);
        }
    }

    unsigned short* dstbase =
        wsb + ((type == 0) ? OQ : (type == 1 ? OK_ : OV)) +
        ((size_t)(i * 4 + b)) * FR_IB + nb * 2048;

    if (type < 2) {
        #pragma unroll
        for (int g = 0; g < 4; ++g) {
            int kd = 8 * g + 4 * h;
            int off = (kd >> 4) * 512 + ((kd >> 3) & 1) * 256 + lq * 8 + (kd & 7);
            *(uintx2*)(dstbase + off) =
                (uintx2){pk_bf16(o0[4 * g], o0[4 * g + 1]),
                         pk_bf16(o0[4 * g + 2], o0[4 * g + 3])};
            int kd2 = kd + 32;
            int off2 = (kd2 >> 4) * 512 + ((kd2 >> 3) & 1) * 256 + lq * 8 + (kd2 & 7);
            *(uintx2*)(dstbase + off2) =
                (uintx2){pk_bf16(o1[4 * g], o1[4 * g + 1]),
                         pk_bf16(o1[4 * g + 2], o1[4 * g + 3])};
        }
    } else {
        #pragma unroll
        for (int g = 0; g < 4; ++g) {
            int off = (g >> 1) * 1024 + (g & 1) * 256 + lq * 8 + 4 * h;
            *(uintx2*)(dstbase + off) =
                (uintx2){pk_bf16(o0[4 * g], o0[4 * g + 1]),
                         pk_bf16(o0[4 * g + 2], o0[4 * g + 3])};
            *(uintx2*)(dstbase + off + 512) =
                (uintx2){pk_bf16(o1[4 * g], o1[4 * g + 1]),
                         pk_bf16(o1[4 * g + 2], o1[4 * g + 3])};
        }
    }
}

// ---------------------------------------------------------------------------
// Kernel: barrier-free MFMA flash attention. Block = 4 waves = 2 q-tiles x
// 2 key-halves; wave streams K/V frags DIRECTLY from global (lane-linear,
// L1-dedup'd with its partner wave). No in-loop barriers/LDS. Epilogue:
// ks-combine via LDS, then write comb as B-frag chunks.
// ---------------------------------------------------------------------------
__global__ __launch_bounds__(256, 4) void attn_kernel(unsigned short* __restrict__ wsb)
{
    __shared__ __align__(16) float fl[4352];

    int bid = blockIdx.x;
    int wid = (bid & 7) * 162 + (bid >> 3);   // XCD-contiguous (1296 = 8*162)
    int s12 = wid / 108;
    int rem = wid % 108;
    int j = s12 >> 2, b = s12 & 3;
    int i = rem / 36;
    int qp = rem % 36;
    int w = threadIdx.x >> 6;
    int ks = w & 1, qloc = w >> 1;
    int lane = threadIdx.x & 63;
    int lq = lane & 31;
    int h = lane >> 5;
    int q0 = (qp * 2 + qloc) * 32;
    int nt = q0 >> 5;

    const unsigned short* qtf = wsb + OQ + ((size_t)(i * 4 + b)) * FR_IB +
                                nt * 2048 + lane * 8;
    const unsigned short* kp = wsb + OK_ + ((size_t)(j * 4 + b)) * FR_IB +
                               (size_t)(ks * 36) * 2048 + lane * 8;
    const unsigned short* vp = wsb + OV + ((size_t)(j * 4 + b)) * FR_IB +
                               (size_t)(ks * 36) * 2048 + lane * 8;

    bf16x8 bq0 = *(const bf16x8*)(qtf + 0);
    bf16x8 bq1 = *(const bf16x8*)(qtf + 512);
    bf16x8 bq2 = *(const bf16x8*)(qtf + 1024);
    bf16x8 bq3 = *(const bf16x8*)(qtf + 1536);

    uintx4 onesw = {0x3F803F80u, 0x3F803F80u, 0x3F803F80u, 0x3F803F80u};
    bf16x8 ones = __builtin_bit_cast(bf16x8, onesw);

    f32x16 o0 = {}, o1 = {}, lacc = {};

    for (int step = 0; step < 36; ++step) {
        const unsigned short* kb = kp + (size_t)step * 2048;
        const unsigned short* vb = vp + (size_t)step * 2048;
        bf16x8 k0 = *(const bf16x8*)(kb + 0 * 512);
        bf16x8 k1 = *(const bf16x8*)(kb + 1 * 512);
        bf16x8 k2 = *(const bf16x8*)(kb + 2 * 512);
        bf16x8 k3 = *(const bf16x8*)(kb + 3 * 512);
        bf16x8 v00 = *(const bf16x8*)(vb + 0 * 512);  // c0,rb0
        bf16x8 v10 = *(const bf16x8*)(vb + 1 * 512);  // c0,rb1
        bf16x8 v01 = *(const bf16x8*)(vb + 2 * 512);  // c1,rb0
        bf16x8 v11 = *(const bf16x8*)(vb + 3 * 512);  // c1,rb1

        f32x16 s = {};
        __builtin_amdgcn_s_setprio(1);
        s = __builtin_amdgcn_mfma_f32_32x32x16_bf16(k0, bq0, s, 0, 0, 0);
        s = __builtin_amdgcn_mfma_f32_32x32x16_bf16(k1, bq1, s, 0, 0, 0);
        s = __builtin_amdgcn_mfma_f32_32x32x16_bf16(k2, bq2, s, 0, 0, 0);
        s = __builtin_amdgcn_mfma_f32_32x32x16_bf16(k3, bq3, s, 0, 0, 0);
        __builtin_amdgcn_s_setprio(0);

        // raw v_exp_f32 — inputs bounded (|S|log2e <= ~12)
        #pragma unroll
        for (int r = 0; r < 16; ++r) s[r] = EXP2(s[r]);

        __builtin_amdgcn_s_setprio(1);
        {   // keys 0..15
            unsigned int a0 = pk_bf16(s[0], s[1]);
            unsigned int a1 = pk_bf16(s[2], s[3]);
            unsigned int b0 = pk_bf16(s[4], s[5]);
            unsigned int b1 = pk_bf16(s[6], s[7]);
            uintx2 r0 = __builtin_amdgcn_permlane32_swap(a0, b0, false, false);
            uintx2 r1 = __builtin_amdgcn_permlane32_swap(a1, b1, false, false);
            uintx4 pwv = {r0[0], r1[0], r0[1], r1[1]};
            bf16x8 pa = __builtin_bit_cast(bf16x8, pwv);
            o0 = __builtin_amdgcn_mfma_f32_32x32x16_bf16(v00, pa, o0, 0, 0, 0);
            o1 = __builtin_amdgcn_mfma_f32_32x32x16_bf16(v10, pa, o1, 0, 0, 0);
            lacc = __builtin_amdgcn_mfma_f32_32x32x16_bf16(ones, pa, lacc, 0, 0, 0);
        }
        {   // keys 16..31
            unsigned int a0 = pk_bf16(s[8], s[9]);
            unsigned int a1 = pk_bf16(s[10], s[11]);
            unsigned int b0 = pk_bf16(s[12], s[13]);
            unsigned int b1 = pk_bf16(s[14], s[15]);
            uintx2 r0 = __builtin_amdgcn_permlane32_swap(a0, b0, false, false);
            uintx2 r1 = __builtin_amdgcn_permlane32_swap(a1, b1, false, false);
            uintx4 pwv = {r0[0], r1[0], r0[1], r1[1]};
            bf16x8 pa = __builtin_bit_cast(bf16x8, pwv);
            o0 = __builtin_amdgcn_mfma_f32_32x32x16_bf16(v01, pa, o0, 0, 0, 0);
            o1 = __builtin_amdgcn_mfma_f32_32x32x16_bf16(v11, pa, o1, 0, 0, 0);
            lacc = __builtin_amdgcn_mfma_f32_32x32x16_bf16(ones, pa, lacc, 0, 0, 0);
        }
        __builtin_amdgcn_s_setprio(0);
    }

    float l_full = lacc[0];

    // ---- combine ks halves: O = (O0+O1)/(l0+l1) ----
    int off = qloc * 2112;
    if (ks == 1) {
        #pragma unroll
        for (int reg = 0; reg < 16; ++reg) {
            fl[off + reg * 64 + lane] = o0[reg];
            fl[off + 1024 + reg * 64 + lane] = o1[reg];
        }
        fl[off + 2048 + lane] = l_full;
    }
    __syncthreads();
    if (ks == 1) return;

    #pragma unroll
    for (int reg = 0; reg < 16; ++reg) {
        o0[reg] += fl[off + reg * 64 + lane];
        o1[reg] += fl[off + 1024 + reg * 64 + lane];
    }
    float l_tot = l_full + fl[off + 2048 + lane];
    __syncthreads();   // fl reusable

    float inv = 1.f / l_tot;
    o0 *= inv; o1 *= inv;

    // transpose O^T -> per-query rows, then write comb as B-frag chunks
    float* tw = fl + qloc * 2080;
    #pragma unroll
    for (int reg = 0; reg < 16; ++reg) {
        int rv = (reg & 3) + 8 * (reg >> 2) + 4 * h;
        tw[lq * 65 + rv] = o0[reg];
        tw[lq * 65 + 32 + rv] = o1[reg];
    }
    // chunk[lane*8+e] = comb[n=q0+(lane&31)][g = i*64 + ksl*16 + 8h + e]
    unsigned short* cb = wsb + OC + (size_t)j * CSTR +
                         ((size_t)((b * 72 + nt) * 12 + i * 4)) * 512;
    #pragma unroll
    for (int ksl = 0; ksl < 4; ++ksl) {
        const float* src = tw + lq * 65 + ksl * 16 + 8 * h;
        uintx4 pwv = {pk_bf16(src[0], src[1]), pk_bf16(src[2], src[3]),
                      pk_bf16(src[4], src[5]), pk_bf16(src[6], src[7])};
        *(uintx4*)(cb + ksl * 512 + lane * 8) = pwv;
    }
}

// ---------------------------------------------------------------------------
// Kernel: MFMA out-projection + sigmoid gate.
// Grid 576: (b, nt of 32n, ch). Wave w -> rb = ch*4+w (32 c-rows).
// acc = sum_j sum_ks mfma(WoF[ks][rb], combjf[j][b][nt][ks]).
// D-map: col = n (lane&31), row = c_local -> fused x*sigmoid store.
// ---------------------------------------------------------------------------
__global__ __launch_bounds__(256) void out_mfma(
    const float* __restrict__ x, const unsigned short* __restrict__ wsb,
    float* __restrict__ out)
{
    int bid = blockIdx.x;
    int ch = bid & 1;
    int nt = (bid >> 1) % 72;
    int b  = bid / 144;
    int n0 = nt * 32;
    int t = threadIdx.x;
    int w = t >> 6, lane = t & 63;
    int lq = lane & 31, h = lane >> 5;
    int rb = ch * 4 + w;

    const unsigned short* wof = wsb + OWOF + lane * 8;
    const unsigned short* cbase = wsb + OC +
        ((size_t)((b * 72 + nt) * 12)) * 512 + lane * 8;

    f32x16 acc = {};
    #pragma unroll
    for (int j = 0; j < 3; ++j) {
        const unsigned short* cj = cbase + (size_t)j * CSTR;
        #pragma unroll
        for (int ksx = 0; ksx < 12; ++ksx) {
            bf16x8 bx = *(const bf16x8*)(cj + ksx * 512);
            bf16x8 a0 = *(const bf16x8*)(wof + (ksx * 8 + rb) * 512);
            acc = __builtin_amdgcn_mfma_f32_32x32x16_bf16(a0, bx, acc, 0, 0, 0);
        }
    }

    int c0 = rb * 32;
    #pragma unroll
    for (int reg = 0; reg < 16; ++reg) {
        int c = c0 + (reg & 3) + 8 * (reg >> 2) + 4 * h;
        size_t idx = ((size_t)(b * CC + c)) * NN_ + n0 + lq;
        float sg = 1.f / (1.f + EXP2(acc[reg] * -1.44269504f));
        out[idx] = x[idx] * sg;
    }
}

extern "C" void kernel_launch(void* const* d_in, const int* in_sizes, int n_in,
                              void* d_out, int out_size, void* d_ws, size_t ws_size,
                              hipStream_t stream) {
    const float* x  = (const float*)d_in[0];
    const float* wq = (const float*)d_in[1];
    const float* wk = (const float*)d_in[2];
    const float* wv = (const float*)d_in[3];
    const float* wo = (const float*)d_in[4];
    unsigned short* wsb = (unsigned short*)d_ws;
    float* out = (float*)d_out;

    prep_kernel<<<300, 256, 0, stream>>>(x, wq, wk, wv, wo, wsb);
    proj_mfma<<<648, 256, 0, stream>>>(wsb);
    attn_kernel<<<1296, 256, 0, stream>>>(wsb);
    out_mfma<<<576, 256, 0, stream>>>(x, wsb, out);
}

// Round 12
// 96.705 us; speedup vs baseline: 4.9229x; 1.0627x over previous
//
#include <hip/hip_runtime.h>

// NestedAttention MI355X round 12: overlap repair in attn — (1) all s_setprio
// removed (m190: hurts multi-wave lockstep), (2) K-frag register ping-pong
// (step+1 prefetch; V just-in-time), (3) l back to VALU add-tree (frees
// matrix pipe + 16 VGPR). Barrier-free main loop kept from round 11.
//
// ws layout (ushort elems):
//   Qf  [3i][4b][72 t][4 f][512]     @ OQ
//   Kf  [3i][4b][72 t][4 f][512]     @ OK_
//   Vf  [3i][4b][72 t][2c][2rb][512] @ OV
//   combjf [3j][4b][72 nt][12 ks][512] @ OC (+j*CSTR)  (B-frag chunks)
//   xf  [4b][72 nb][16 ks][512]      @ OXF
//   Wf  [9 s][16 ks][2 rb][512]      @ OWF
//   WoF [12 ks][8 rb][512]           @ OWOF
// Frag chunk: chunk[lane*8+e] = Op[idx=lane&31][k=8*(lane>>5)+e]

#define BB 4
#define CC 256
#define NN_ 2304
#define RR 64

#define OQ 0
#define OK_ 1769472
#define OV 3538944
#define OC 5308416
#define CSTR 1769472
#define FR_IB 147456
#define OXF 10616832
#define OWF 12976128
#define OWOF 13123584

typedef __bf16 bf16x8 __attribute__((ext_vector_type(8)));
typedef float f32x16 __attribute__((ext_vector_type(16)));
typedef unsigned short ushort8 __attribute__((ext_vector_type(8)));
typedef unsigned int uintx2 __attribute__((ext_vector_type(2)));
typedef unsigned int uintx4 __attribute__((ext_vector_type(4)));

#if __has_builtin(__builtin_amdgcn_exp2f)
#define EXP2(x) __builtin_amdgcn_exp2f(x)
#else
#define EXP2(x) exp2f(x)
#endif

__device__ __forceinline__ float bf2f(unsigned short s) {
    unsigned int u = ((unsigned int)s) << 16;
    return __builtin_bit_cast(float, u);
}
__device__ __forceinline__ unsigned int pk_bf16(float lo, float hi) {
    unsigned int r;
    asm("v_cvt_pk_bf16_f32 %0, %1, %2" : "=v"(r) : "v"(lo), "v"(hi));
    return r;
}

// ---------------------------------------------------------------------------
// Prep: bid<9 weights->A-frags; bid<12 wo->A-frags; else x->B-frags.
// ---------------------------------------------------------------------------
__global__ __launch_bounds__(256) void prep_kernel(
    const float* __restrict__ x, const float* __restrict__ wq,
    const float* __restrict__ wk, const float* __restrict__ wv,
    const float* __restrict__ wo, unsigned short* __restrict__ wsb)
{
    int bid = blockIdx.x;
    int t = threadIdx.x;
    if (bid < 9) {
        int s = bid;
        int type = s / 3, i = s % 3;
        const float* wsel = (type == 0) ? wq : (type == 1 ? wk : wv);
        const float scale = (type == 0) ? 0.18033688011112042f : 1.0f;  // 0.125*log2e
        unsigned short* dst = wsb + OWF + s * 16384;
        #pragma unroll
        for (int p = 0; p < 8; ++p) {
            int u = t + 256 * p;
            int ks = u >> 7, rb = (u >> 6) & 1, lo = u & 63;
            int row = rb * 32 + (lo & 31), c = ks * 16 + 8 * (lo >> 5);
            const float* src = wsel + ((i * 64 + row) * 256 + c);
            float4 f0 = *(const float4*)(src);
            float4 f1 = *(const float4*)(src + 4);
            uintx4 pwv = {pk_bf16(f0.x * scale, f0.y * scale),
                          pk_bf16(f0.z * scale, f0.w * scale),
                          pk_bf16(f1.x * scale, f1.y * scale),
                          pk_bf16(f1.z * scale, f1.w * scale)};
            *(uintx4*)(dst + (ks * 2 + rb) * 512 + lo * 8) = pwv;
        }
        return;
    }
    if (bid < 12) {
        int bb = bid - 9;
        #pragma unroll
        for (int p = 0; p < 8; ++p) {
            int u = t + 256 * p;
            int cg = bb * 32 + (u >> 6);
            int lane = u & 63;
            int ks = cg >> 3, rb = cg & 7;
            int row = rb * 32 + (lane & 31);
            int g = ks * 16 + 8 * (lane >> 5);
            const float* src = wo + row * 192 + g;
            float4 f0 = *(const float4*)(src);
            float4 f1 = *(const float4*)(src + 4);
            uintx4 pwv = {pk_bf16(f0.x, f0.y), pk_bf16(f0.z, f0.w),
                          pk_bf16(f1.x, f1.y), pk_bf16(f1.z, f1.w)};
            *(uintx4*)(wsb + OWOF + cg * 512 + lane * 8) = pwv;
        }
        return;
    }
    __shared__ __align__(16) float xs[64 * 132];
    int xb = bid - 12;
    int cq  = xb & 3;
    int nt2 = (xb >> 2) % 18;
    int b   = xb / 72;
    int c0 = cq * 64, n0 = nt2 * 128;
    #pragma unroll
    for (int p = 0; p < 8; ++p) {
        int u = t + 256 * p;
        int cl = u >> 5, nq = (u & 31) * 4;
        *(float4*)&xs[cl * 132 + nq] =
            *(const float4*)&x[((size_t)(b * CC + c0 + cl)) * NN_ + n0 + nq];
    }
    __syncthreads();
    unsigned short* xfb = wsb + OXF + ((size_t)b) * 72 * 16 * 512;
    #pragma unroll
    for (int p = 0; p < 4; ++p) {
        int u = t + 256 * p;
        int nb_l = u >> 8, ks_l = (u >> 6) & 3, lo = u & 63;
        int hh = lo >> 5, idx = lo & 31;
        int clb = ks_l * 16 + 8 * hh;
        int nn = nb_l * 32 + idx;
        unsigned int pw[4];
        #pragma unroll
        for (int d = 0; d < 4; ++d) {
            float a  = xs[(clb + 2 * d) * 132 + nn];
            float bb2 = xs[(clb + 2 * d + 1) * 132 + nn];
            pw[d] = pk_bf16(a, bb2);
        }
        int nb = nt2 * 4 + nb_l, ks = cq * 4 + ks_l;
        *(uintx4*)(xfb + (nb * 16 + ks) * 512 + lo * 8) =
            (uintx4){pw[0], pw[1], pw[2], pw[3]};
    }
}

// ---------------------------------------------------------------------------
// Kernel: MFMA projection (unchanged structure).
// ---------------------------------------------------------------------------
__global__ __launch_bounds__(256) void proj_mfma(unsigned short* __restrict__ wsb)
{
    int bid = blockIdx.x;
    int s = bid / 72;
    int rem = bid % 72;
    int b = rem / 18, nb4 = rem % 18;
    int type = s / 3, i = s % 3;
    int t = threadIdx.x;
    int w = t >> 6, lane = t & 63;
    int lq = lane & 31, h = lane >> 5;
    int nb = nb4 * 4 + w;

    const unsigned short* wf = wsb + OWF + s * 16384 + lane * 8;
    const unsigned short* xf = wsb + OXF + ((size_t)(b * 72 + nb) * 16) * 512 + lane * 8;

    f32x16 o0 = {}, o1 = {};
    if (type < 2) {
        #pragma unroll
        for (int ks = 0; ks < 16; ++ks) {
            bf16x8 a0 = *(const bf16x8*)(wf + ks * 1024);
            bf16x8 a1 = *(const bf16x8*)(wf + ks * 1024 + 512);
            bf16x8 bx = *(const bf16x8*)(xf + ks * 512);
            o0 = __builtin_amdgcn_mfma_f32_32x32x16_bf16(a0, bx, o0, 0, 0, 0);
            o1 = __builtin_amdgcn_mfma_f32_32x32x16_bf16(a1, bx, o1, 0, 0, 0);
        }
    } else {
        #pragma unroll
        for (int ks = 0; ks < 16; ++ks) {
            bf16x8 a0 = *(const bf16x8*)(wf + ks * 1024);
            bf16x8 a1 = *(const bf16x8*)(wf + ks * 1024 + 512);
            bf16x8 bx = *(const bf16x8*)(xf + ks * 512);
            o0 = __builtin_amdgcn_mfma_f32_32x32x16_bf16(bx, a0, o0, 0, 0, 0);
            o1 = __builtin_amdgcn_mfma_f32_32x32x16_bf16(bx, a1, o1, 0, 0, 0);
        }
    }

    unsigned short* dstbase =
        wsb + ((type == 0) ? OQ : (type == 1 ? OK_ : OV)) +
        ((size_t)(i * 4 + b)) * FR_IB + nb * 2048;

    if (type < 2) {
        #pragma unroll
        for (int g = 0; g < 4; ++g) {
            int kd = 8 * g + 4 * h;
            int off = (kd >> 4) * 512 + ((kd >> 3) & 1) * 256 + lq * 8 + (kd & 7);
            *(uintx2*)(dstbase + off) =
                (uintx2){pk_bf16(o0[4 * g], o0[4 * g + 1]),
                         pk_bf16(o0[4 * g + 2], o0[4 * g + 3])};
            int kd2 = kd + 32;
            int off2 = (kd2 >> 4) * 512 + ((kd2 >> 3) & 1) * 256 + lq * 8 + (kd2 & 7);
            *(uintx2*)(dstbase + off2) =
                (uintx2){pk_bf16(o1[4 * g], o1[4 * g + 1]),
                         pk_bf16(o1[4 * g + 2], o1[4 * g + 3])};
        }
    } else {
        #pragma unroll
        for (int g = 0; g < 4; ++g) {
            int off = (g >> 1) * 1024 + (g & 1) * 256 + lq * 8 + 4 * h;
            *(uintx2*)(dstbase + off) =
                (uintx2){pk_bf16(o0[4 * g], o0[4 * g + 1]),
                         pk_bf16(o0[4 * g + 2], o0[4 * g + 3])};
            *(uintx2*)(dstbase + off + 512) =
                (uintx2){pk_bf16(o1[4 * g], o1[4 * g + 1]),
                         pk_bf16(o1[4 * g + 2], o1[4 * g + 3])};
        }
    }
}

// ---------------------------------------------------------------------------
// Kernel: barrier-free MFMA flash attention, K ping-pong prefetch, no setprio.
// Block = 4 waves = 2 q-tiles x 2 key-halves. V loads just-in-time (hide
// under QK+exp). l via VALU add-tree. Epilogue unchanged.
// ---------------------------------------------------------------------------
__global__ __launch_bounds__(256, 4) void attn_kernel(unsigned short* __restrict__ wsb)
{
    __shared__ __align__(16) float fl[4352];

    int bid = blockIdx.x;
    int wid = (bid & 7) * 162 + (bid >> 3);   // XCD-contiguous (1296 = 8*162)
    int s12 = wid / 108;
    int rem = wid % 108;
    int j = s12 >> 2, b = s12 & 3;
    int i = rem / 36;
    int qp = rem % 36;
    int w = threadIdx.x >> 6;
    int ks = w & 1, qloc = w >> 1;
    int lane = threadIdx.x & 63;
    int lq = lane & 31;
    int h = lane >> 5;
    int q0 = (qp * 2 + qloc) * 32;
    int nt = q0 >> 5;

    const unsigned short* qtf = wsb + OQ + ((size_t)(i * 4 + b)) * FR_IB +
                                nt * 2048 + lane * 8;
    const unsigned short* kp = wsb + OK_ + ((size_t)(j * 4 + b)) * FR_IB +
                               (size_t)(ks * 36) * 2048 + lane * 8;
    const unsigned short* vp = wsb + OV + ((size_t)(j * 4 + b)) * FR_IB +
                               (size_t)(ks * 36) * 2048 + lane * 8;

    bf16x8 bq0 = *(const bf16x8*)(qtf + 0);
    bf16x8 bq1 = *(const bf16x8*)(qtf + 512);
    bf16x8 bq2 = *(const bf16x8*)(qtf + 1024);
    bf16x8 bq3 = *(const bf16x8*)(qtf + 1536);

    f32x16 o0 = {}, o1 = {};
    float l_loc = 0.f;

    // one 32-key step: K frags already in regs; V loaded just-in-time
    auto compute_step = [&](bf16x8 k0, bf16x8 k1, bf16x8 k2, bf16x8 k3,
                            int step) {
        const unsigned short* vb = vp + (size_t)step * 2048;
        // issue V loads first so they land before the PV phase
        bf16x8 v00 = *(const bf16x8*)(vb + 0 * 512);  // c0,rb0
        bf16x8 v10 = *(const bf16x8*)(vb + 1 * 512);  // c0,rb1
        bf16x8 v01 = *(const bf16x8*)(vb + 2 * 512);  // c1,rb0
        bf16x8 v11 = *(const bf16x8*)(vb + 3 * 512);  // c1,rb1

        f32x16 s = {};
        s = __builtin_amdgcn_mfma_f32_32x32x16_bf16(k0, bq0, s, 0, 0, 0);
        s = __builtin_amdgcn_mfma_f32_32x32x16_bf16(k1, bq1, s, 0, 0, 0);
        s = __builtin_amdgcn_mfma_f32_32x32x16_bf16(k2, bq2, s, 0, 0, 0);
        s = __builtin_amdgcn_mfma_f32_32x32x16_bf16(k3, bq3, s, 0, 0, 0);

        // raw v_exp_f32 — inputs bounded (|S|log2e <= ~12)
        #pragma unroll
        for (int r = 0; r < 16; ++r) s[r] = EXP2(s[r]);
        l_loc += ((s[0] + s[1]) + (s[2] + s[3])) + ((s[4] + s[5]) + (s[6] + s[7])) +
                 ((s[8] + s[9]) + (s[10] + s[11])) + ((s[12] + s[13]) + (s[14] + s[15]));

        {   // keys 0..15
            unsigned int a0 = pk_bf16(s[0], s[1]);
            unsigned int a1 = pk_bf16(s[2], s[3]);
            unsigned int b0 = pk_bf16(s[4], s[5]);
            unsigned int b1 = pk_bf16(s[6], s[7]);
            uintx2 r0 = __builtin_amdgcn_permlane32_swap(a0, b0, false, false);
            uintx2 r1 = __builtin_amdgcn_permlane32_swap(a1, b1, false, false);
            uintx4 pwv = {r0[0], r1[0], r0[1], r1[1]};
            bf16x8 pa = __builtin_bit_cast(bf16x8, pwv);
            o0 = __builtin_amdgcn_mfma_f32_32x32x16_bf16(v00, pa, o0, 0, 0, 0);
            o1 = __builtin_amdgcn_mfma_f32_32x32x16_bf16(v10, pa, o1, 0, 0, 0);
        }
        {   // keys 16..31
            unsigned int a0 = pk_bf16(s[8], s[9]);
            unsigned int a1 = pk_bf16(s[10], s[11]);
            unsigned int b0 = pk_bf16(s[12], s[13]);
            unsigned int b1 = pk_bf16(s[14], s[15]);
            uintx2 r0 = __builtin_amdgcn_permlane32_swap(a0, b0, false, false);
            uintx2 r1 = __builtin_amdgcn_permlane32_swap(a1, b1, false, false);
            uintx4 pwv = {r0[0], r1[0], r0[1], r1[1]};
            bf16x8 pa = __builtin_bit_cast(bf16x8, pwv);
            o0 = __builtin_amdgcn_mfma_f32_32x32x16_bf16(v01, pa, o0, 0, 0, 0);
            o1 = __builtin_amdgcn_mfma_f32_32x32x16_bf16(v11, pa, o1, 0, 0, 0);
        }
    };

    // ---- K ping-pong: preload step 0 into set A ----
    bf16x8 kA0 = *(const bf16x8*)(kp + 0 * 512);
    bf16x8 kA1 = *(const bf16x8*)(kp + 1 * 512);
    bf16x8 kA2 = *(const bf16x8*)(kp + 2 * 512);
    bf16x8 kA3 = *(const bf16x8*)(kp + 3 * 512);

    for (int step = 0; step < 36; step += 2) {
        // prefetch K for step+1 into set B
        const unsigned short* kbB = kp + (size_t)(step + 1) * 2048;
        bf16x8 kB0 = *(const bf16x8*)(kbB + 0 * 512);
        bf16x8 kB1 = *(const bf16x8*)(kbB + 1 * 512);
        bf16x8 kB2 = *(const bf16x8*)(kbB + 2 * 512);
        bf16x8 kB3 = *(const bf16x8*)(kbB + 3 * 512);

        compute_step(kA0, kA1, kA2, kA3, step);

        // prefetch K for step+2 into set A (wrap to 0 on last pair; unused)
        int nx = (step + 2 < 36) ? (step + 2) : 0;
        const unsigned short* kbA = kp + (size_t)nx * 2048;
        kA0 = *(const bf16x8*)(kbA + 0 * 512);
        kA1 = *(const bf16x8*)(kbA + 1 * 512);
        kA2 = *(const bf16x8*)(kbA + 2 * 512);
        kA3 = *(const bf16x8*)(kbA + 3 * 512);

        compute_step(kB0, kB1, kB2, kB3, step + 1);
    }

    float l_full = l_loc + __shfl_xor(l_loc, 32);

    // ---- combine ks halves: O = (O0+O1)/(l0+l1) ----
    int off = qloc * 2112;
    if (ks == 1) {
        #pragma unroll
        for (int reg = 0; reg < 16; ++reg) {
            fl[off + reg * 64 + lane] = o0[reg];
            fl[off + 1024 + reg * 64 + lane] = o1[reg];
        }
        fl[off + 2048 + lane] = l_full;
    }
    __syncthreads();
    if (ks == 1) return;

    #pragma unroll
    for (int reg = 0; reg < 16; ++reg) {
        o0[reg] += fl[off + reg * 64 + lane];
        o1[reg] += fl[off + 1024 + reg * 64 + lane];
    }
    float l_tot = l_full + fl[off + 2048 + lane];
    __syncthreads();   // fl reusable

    float inv = 1.f / l_tot;
    o0 *= inv; o1 *= inv;

    // transpose O^T -> per-query rows, then write comb as B-frag chunks
    float* tw = fl + qloc * 2080;
    #pragma unroll
    for (int reg = 0; reg < 16; ++reg) {
        int rv = (reg & 3) + 8 * (reg >> 2) + 4 * h;
        tw[lq * 65 + rv] = o0[reg];
        tw[lq * 65 + 32 + rv] = o1[reg];
    }
    // chunk[lane*8+e] = comb[n=q0+(lane&31)][g = i*64 + ksl*16 + 8h + e]
    unsigned short* cb = wsb + OC + (size_t)j * CSTR +
                         ((size_t)((b * 72 + nt) * 12 + i * 4)) * 512;
    #pragma unroll
    for (int ksl = 0; ksl < 4; ++ksl) {
        const float* src = tw + lq * 65 + ksl * 16 + 8 * h;
        uintx4 pwv = {pk_bf16(src[0], src[1]), pk_bf16(src[2], src[3]),
                      pk_bf16(src[4], src[5]), pk_bf16(src[6], src[7])};
        *(uintx4*)(cb + ksl * 512 + lane * 8) = pwv;
    }
}

// ---------------------------------------------------------------------------
// Kernel: MFMA out-projection + sigmoid gate.
// ---------------------------------------------------------------------------
__global__ __launch_bounds__(256) void out_mfma(
    const float* __restrict__ x, const unsigned short* __restrict__ wsb,
    float* __restrict__ out)
{
    int bid = blockIdx.x;
    int ch = bid & 1;
    int nt = (bid >> 1) % 72;
    int b  = bid / 144;
    int n0 = nt * 32;
    int t = threadIdx.x;
    int w = t >> 6, lane = t & 63;
    int lq = lane & 31, h = lane >> 5;
    int rb = ch * 4 + w;

    const unsigned short* wof = wsb + OWOF + lane * 8;
    const unsigned short* cbase = wsb + OC +
        ((size_t)((b * 72 + nt) * 12)) * 512 + lane * 8;

    f32x16 acc = {};
    #pragma unroll
    for (int j = 0; j < 3; ++j) {
        const unsigned short* cj = cbase + (size_t)j * CSTR;
        #pragma unroll
        for (int ksx = 0; ksx < 12; ++ksx) {
            bf16x8 bx = *(const bf16x8*)(cj + ksx * 512);
            bf16x8 a0 = *(const bf16x8*)(wof + (ksx * 8 + rb) * 512);
            acc = __builtin_amdgcn_mfma_f32_32x32x16_bf16(a0, bx, acc, 0, 0, 0);
        }
    }

    int c0 = rb * 32;
    #pragma unroll
    for (int reg = 0; reg < 16; ++reg) {
        int c = c0 + (reg & 3) + 8 * (reg >> 2) + 4 * h;
        size_t idx = ((size_t)(b * CC + c)) * NN_ + n0 + lq;
        float sg = 1.f / (1.f + EXP2(acc[reg] * -1.44269504f));
        out[idx] = x[idx] * sg;
    }
}

extern "C" void kernel_launch(void* const* d_in, const int* in_sizes, int n_in,
                              void* d_out, int out_size, void* d_ws, size_t ws_size,
                              hipStream_t stream) {
    const float* x  = (const float*)d_in[0];
    const float* wq = (const float*)d_in[1];
    const float* wk = (const float*)d_in[2];
    const float* wv = (const float*)d_in[3];
    const float* wo = (const float*)d_in[4];
    unsigned short* wsb = (unsigned short*)d_ws;
    float* out = (float*)d_out;

    prep_kernel<<<300, 256, 0, stream>>>(x, wq, wk, wv, wo, wsb);
    proj_mfma<<<648, 256, 0, stream>>>(wsb);
    attn_kernel<<<1296, 256, 0, stream>>>(wsb);
    out_mfma<<<576, 256, 0, stream>>>(x, wsb, out);
}